// Round 4
// baseline (880.819 us; speedup 1.0000x reference)
//
#include <hip/hip_runtime.h>
#include <math.h>

#define BB 4
#define CC 64
#define HH 128
#define WW 128
#define HWP 16384

// ---------------- K0: transpose offset-conv weights to [grp][c][k*9+t] (stride 96)
__global__ __launch_bounds__(256) void k0_wt(
    const float* __restrict__ ow, float* __restrict__ owt)
{
    int i = blockIdx.x*256 + threadIdx.x;      // over 27*128*9 = 31104
    if (i < 27*128*9) {
        int t  = i % 9;
        int r  = i / 9;
        int c  = r % 128;
        int ko = r / 128;                      // 0..26
        int grp = ko / 9, kk = ko % 9;
        owt[(grp*128 + c)*96 + kk*9 + t] = ow[i];
    }
}

// ---------------- K1: 3x3 conv over concat[f1,f3] -> om [B][27][H][W]
// No LDS. Weights read via wave-uniform indices -> SGPRs (scalar loads).
// Group 2 (channels 18..26) gets sigmoid applied (mask).
__global__ __launch_bounds__(256) void k1_offset_conv(
    const float* __restrict__ f1, const float* __restrict__ f3,
    const float* __restrict__ owt, const float* __restrict__ ob,
    float* __restrict__ om)
{
    int grp = blockIdx.y;          // 0..2
    int pix = blockIdx.x*256 + threadIdx.x;
    int b = pix >> 14;
    int y = (pix >> 7) & 127;
    int x = pix & 127;

    int   toff[9];
    float tval[9];
#pragma unroll
    for (int t = 0; t < 9; ++t) {
        int yy = y + t/3 - 1;
        int xx = x + (t % 3) - 1;
        bool ok = ((unsigned)yy < (unsigned)HH) && ((unsigned)xx < (unsigned)WW);
        tval[t] = ok ? 1.f : 0.f;
        toff[t] = ok ? (yy*WW + xx) : 0;
    }

    float acc[9];
#pragma unroll
    for (int k = 0; k < 9; ++k) acc[k] = ob[grp*9 + k];

    const float* base0 = f1 + ((size_t)(b*CC) << 14);
    const float* base1 = f3 + ((size_t)(b*CC) << 14);
    const float* wgs = owt + grp*128*96;       // uniform base

    for (int half = 0; half < 2; ++half) {
        const float* srcb = (half == 0) ? base0 : base1;
        for (int c0 = 0; c0 < 64; ++c0) {
            const float* src = srcb + (c0 << 14);
            float v[9];
#pragma unroll
            for (int t = 0; t < 9; ++t) v[t] = tval[t] * src[toff[t]];
            const float* wr = wgs + (half*64 + c0)*96;   // uniform
#pragma unroll
            for (int k = 0; k < 9; ++k)
#pragma unroll
                for (int t = 0; t < 9; ++t)
                    acc[k] = fmaf(v[t], wr[k*9 + t], acc[k]);
        }
    }

    int obase = ((b*27 + grp*9) << 14) + (y << 7) + x;
#pragma unroll
    for (int k = 0; k < 9; ++k) {
        float a = acc[k];
        if (grp == 2) a = 1.f / (1.f + __expf(-a));   // sigmoid for mask group
        om[obase + (k << 14)] = a;
    }
}

// ---------------- K2: deformable conv; writes aligned into d_out
// block = half-row (64 px), grid 1024; 8 chunks of 8 input channels.
// LDS: sl[72][64] + wl[64][76] = 37888 B.
// __launch_bounds__(256,4): force VGPR<=128 so 4 blocks/CU actually materialize.
// #pragma unroll 1 on the k-loop: clang auto-unrolled it (184 VGPR in R2/R3).
__global__ __launch_bounds__(256, 4) void k2_deform(
    const float* __restrict__ f1, const float* __restrict__ mw,
    const float* __restrict__ om, float* __restrict__ aligned)
{
    extern __shared__ float lds[];
    float* sl = lds;             // [72][64]
    float* wl = lds + 72*64;     // [64][76] (ck stride padded to 76)

    int blk = blockIdx.x;        // b(2) y(7) xh(1)
    int xh = blk & 1;
    int y  = (blk >> 1) & 127;
    int b  = blk >> 8;

    int tid = threadIdx.x;
    int px  = tid & 63;          // local x within half-row
    int cs  = tid >> 6;          // 0..3 channel-slot
    int gx  = xh*64 + px;

    int oo = tid & 15;
    int pg = tid >> 4;           // 0..15

    float acc[4][4];
#pragma unroll
    for (int j = 0; j < 4; ++j)
#pragma unroll
        for (int p = 0; p < 4; ++p) acc[j][p] = 0.f;

    const float* omb = om + ((b*27) << 14) + (y << 7);
    const float* f1b = f1 + ((size_t)(b*CC) << 14);

#pragma unroll 1
    for (int chunk = 0; chunk < 8; ++chunk) {
        // stage weights: wl[o][ck] = mw[o*576 + chunk*72 + ck]
        for (int q = tid; q < 64*18; q += 256) {
            int o = q / 18;
            int ck4 = (q - o*18) * 4;
            float4 wv = *(const float4*)&mw[o*576 + chunk*72 + ck4];
            *(float4*)&wl[o*76 + ck4] = wv;
        }

        // phase A: bilinear sampling, 2 channels per thread.
        // unroll 1: keep VGPR low; offset reloads are coalesced L2 hits.
#pragma unroll 1
        for (int k = 0; k < 9; ++k) {
            float off0 = omb[((2*k)   << 14) + gx];
            float off1 = omb[((2*k+1) << 14) + gx];
            float mk   = omb[((18+k)  << 14) + gx];   // already sigmoided in K1

            float pyf = (float)y  + (float)(k/3) - 1.f + off0;
            float pxg = (float)gx + (float)(k%3) - 1.f + off1;
            float fy = floorf(pyf), fx = floorf(pxg);
            int y0 = (int)fy, x0 = (int)fx;
            float wy = pyf - fy, wx = pxg - fx;
            float oy = 1.f - wy, ox = 1.f - wx;
            float w00 = oy*ox, w01 = oy*wx, w10 = wy*ox, w11 = wy*wx;
            bool yv0 = (unsigned)y0     < (unsigned)HH;
            bool yv1 = (unsigned)(y0+1) < (unsigned)HH;
            bool xv0 = (unsigned)x0     < (unsigned)WW;
            bool xv1 = (unsigned)(x0+1) < (unsigned)WW;
            int i00 = y0*WW + x0;

#pragma unroll
            for (int cl = 0; cl < 2; ++cl) {
                int c_loc = cs*2 + cl;
                int c = chunk*8 + c_loc;
                const float* src = f1b + (c << 14);
                float s = 0.f;
                if (yv0 && xv0) s += w00 * src[i00];
                if (yv0 && xv1) s += w01 * src[i00 + 1];
                if (yv1 && xv0) s += w10 * src[i00 + WW];
                if (yv1 && xv1) s += w11 * src[i00 + WW + 1];
                sl[(c_loc*9 + k)*64 + px] = s * mk;
            }
        }
        __syncthreads();

        // phase B: acc[j][p] += wl[oo+16j][ck+i] * sl[ck+i][pg*4+p]
        for (int ck = 0; ck < 72; ck += 4) {
            float4 s0 = *(const float4*)&sl[(ck+0)*64 + pg*4];
            float4 s1 = *(const float4*)&sl[(ck+1)*64 + pg*4];
            float4 s2 = *(const float4*)&sl[(ck+2)*64 + pg*4];
            float4 s3 = *(const float4*)&sl[(ck+3)*64 + pg*4];
#pragma unroll
            for (int j = 0; j < 4; ++j) {
                float4 wv = *(const float4*)&wl[(oo + 16*j)*76 + ck];
                acc[j][0] += wv.x*s0.x + wv.y*s1.x + wv.z*s2.x + wv.w*s3.x;
                acc[j][1] += wv.x*s0.y + wv.y*s1.y + wv.z*s2.y + wv.w*s3.y;
                acc[j][2] += wv.x*s0.z + wv.y*s1.z + wv.z*s2.z + wv.w*s3.z;
                acc[j][3] += wv.x*s0.w + wv.y*s1.w + wv.z*s2.w + wv.w*s3.w;
            }
        }
        __syncthreads();
    }

#pragma unroll
    for (int j = 0; j < 4; ++j) {
        int o = oo + 16*j;
        float4 v = make_float4(acc[j][0], acc[j][1], acc[j][2], acc[j][3]);
        *(float4*)&aligned[((b*CC + o) << 14) + (y << 7) + xh*64 + pg*4] = v;
    }
}

// ---------------- K3: per-channel partial sum / sumsq; grid 128 = (c, batch-half)
__global__ __launch_bounds__(256) void k3_stats(
    const float* __restrict__ a, float* __restrict__ stats)
{
    int c = blockIdx.x & 63;
    int half = blockIdx.x >> 6;
    int tid = threadIdx.x;
    float s = 0.f, s2 = 0.f;
    for (int bimg = half*2; bimg < half*2 + 2; ++bimg) {
        const float* base = a + ((size_t)(bimg*CC + c) << 14);
        for (int i = tid*4; i < HWP; i += 256*4) {
            float4 v = *(const float4*)&base[i];
            s  += v.x + v.y + v.z + v.w;
            s2 += v.x*v.x + v.y*v.y + v.z*v.z + v.w*v.w;
        }
    }
    for (int off = 32; off > 0; off >>= 1) {
        s  += __shfl_down(s,  off, 64);
        s2 += __shfl_down(s2, off, 64);
    }
    __shared__ float rs[4], rs2[4];
    int w = tid >> 6;
    if ((tid & 63) == 0) { rs[w] = s; rs2[w] = s2; }
    __syncthreads();
    if (tid == 0) {
        stats[half*128 + c]      = rs[0] + rs[1] + rs[2] + rs[3];
        stats[half*128 + 64 + c] = rs2[0] + rs2[1] + rs2[2] + rs2[3];
    }
}

// ---------------- K4: in-place normalize + affine (combines the 2 partials)
__global__ __launch_bounds__(256) void k4_norm(
    float* __restrict__ a, const float* __restrict__ stats,
    const float* __restrict__ gamma, const float* __restrict__ beta)
{
    const float invN = 1.f / 65536.f;
    int n4 = (BB*CC*HWP) / 4;
    for (int i4 = blockIdx.x*256 + threadIdx.x; i4 < n4; i4 += gridDim.x*256) {
        int c = (i4 >> 12) & 63;
        float mean = (stats[c] + stats[128 + c]) * invN;
        float var  = (stats[64 + c] + stats[192 + c]) * invN - mean*mean;
        float sc = gamma[c] * rsqrtf(var + 1e-5f);
        float sh = beta[c] - mean*sc;
        float4 v = ((const float4*)a)[i4];
        v.x = v.x*sc + sh; v.y = v.y*sc + sh;
        v.z = v.z*sc + sh; v.w = v.w*sc + sh;
        ((float4*)a)[i4] = v;
    }
}

extern "C" void kernel_launch(void* const* d_in, const int* in_sizes, int n_in,
                              void* d_out, int out_size, void* d_ws, size_t ws_size,
                              hipStream_t stream)
{
    const float* f1    = (const float*)d_in[0];
    const float* f3    = (const float*)d_in[1];
    const float* ow    = (const float*)d_in[2];
    const float* ob    = (const float*)d_in[3];
    const float* mw    = (const float*)d_in[4];
    const float* gamma = (const float*)d_in[5];
    const float* beta  = (const float*)d_in[6];
    float* out = (float*)d_out;

    float* om    = (float*)d_ws;               // [4][27][128][128] = 7,077,888 B
    float* stats = om + 4*27*HWP;              // [256] floats
    float* owt   = stats + 256;                // [3][128][96] = 147,456 B

    const int lds2 = (72*64 + 64*76)*4;        // 37,888 B
    (void)hipFuncSetAttribute((const void*)k2_deform,
        hipFuncAttributeMaxDynamicSharedMemorySize, lds2);

    hipLaunchKernelGGL(k0_wt, dim3(122), dim3(256), 0, stream, ow, owt);
    hipLaunchKernelGGL(k1_offset_conv, dim3(256, 3), dim3(256), 0, stream,
                       f1, f3, owt, ob, om);
    hipLaunchKernelGGL(k2_deform, dim3(1024), dim3(256), lds2, stream,
                       f1, mw, om, out);
    hipLaunchKernelGGL(k3_stats, dim3(128), dim3(256), 0, stream, out, stats);
    hipLaunchKernelGGL(k4_norm, dim3(2048), dim3(256), 0, stream,
                       out, stats, gamma, beta);
}

// Round 5
// 328.253 us; speedup vs baseline: 2.6834x; 2.6834x over previous
//
#include <hip/hip_runtime.h>
#include <math.h>

#define BB 4
#define CC 64
#define HH 128
#define WW 128
#define HWP 16384

// ---------------- K0: transpose offset-conv weights to [grp][c][k*9+t] (stride 96)
__global__ __launch_bounds__(256) void k0_wt(
    const float* __restrict__ ow, float* __restrict__ owt)
{
    int i = blockIdx.x*256 + threadIdx.x;      // over 27*128*9 = 31104
    if (i < 27*128*9) {
        int t  = i % 9;
        int r  = i / 9;
        int c  = r % 128;
        int ko = r / 128;                      // 0..26
        int grp = ko / 9, kk = ko % 9;
        owt[(grp*128 + c)*96 + kk*9 + t] = ow[i];
    }
}

// ---------------- K1: 3x3 conv over concat[f1,f3] -> om [B][27][H][W]
// No LDS. Weights read via wave-uniform indices -> SGPRs (scalar loads).
// Group 2 (channels 18..26) gets sigmoid applied (mask).
__global__ __launch_bounds__(256) void k1_offset_conv(
    const float* __restrict__ f1, const float* __restrict__ f3,
    const float* __restrict__ owt, const float* __restrict__ ob,
    float* __restrict__ om)
{
    int grp = blockIdx.y;          // 0..2
    int pix = blockIdx.x*256 + threadIdx.x;
    int b = pix >> 14;
    int y = (pix >> 7) & 127;
    int x = pix & 127;

    int   toff[9];
    float tval[9];
#pragma unroll
    for (int t = 0; t < 9; ++t) {
        int yy = y + t/3 - 1;
        int xx = x + (t % 3) - 1;
        bool ok = ((unsigned)yy < (unsigned)HH) && ((unsigned)xx < (unsigned)WW);
        tval[t] = ok ? 1.f : 0.f;
        toff[t] = ok ? (yy*WW + xx) : 0;
    }

    float acc[9];
#pragma unroll
    for (int k = 0; k < 9; ++k) acc[k] = ob[grp*9 + k];

    const float* base0 = f1 + ((size_t)(b*CC) << 14);
    const float* base1 = f3 + ((size_t)(b*CC) << 14);
    const float* wgs = owt + grp*128*96;       // uniform base

    for (int half = 0; half < 2; ++half) {
        const float* srcb = (half == 0) ? base0 : base1;
        for (int c0 = 0; c0 < 64; ++c0) {
            const float* src = srcb + (c0 << 14);
            float v[9];
#pragma unroll
            for (int t = 0; t < 9; ++t) v[t] = tval[t] * src[toff[t]];
            const float* wr = wgs + (half*64 + c0)*96;   // uniform
#pragma unroll
            for (int k = 0; k < 9; ++k)
#pragma unroll
                for (int t = 0; t < 9; ++t)
                    acc[k] = fmaf(v[t], wr[k*9 + t], acc[k]);
        }
    }

    int obase = ((b*27 + grp*9) << 14) + (y << 7) + x;
#pragma unroll
    for (int k = 0; k < 9; ++k) {
        float a = acc[k];
        if (grp == 2) a = 1.f / (1.f + __expf(-a));   // sigmoid for mask group
        om[obase + (k << 14)] = a;
    }
}

// ---------------- K2: deformable conv; writes aligned into d_out
// block = half-row (64 px), grid 1024; 8 chunks of 8 input channels.
// LDS: sl[72][64] + wl[64][76] = 37888 B (4 blocks/CU possible).
// NO wave-min cap (R4's (256,4) demoted acc to scratch: 2.3 GB spill traffic).
// #pragma unroll 1 keeps natural VGPR low; named float4 accumulators cannot
// be demoted to indexed local memory.
__global__ __launch_bounds__(256) void k2_deform(
    const float* __restrict__ f1, const float* __restrict__ mw,
    const float* __restrict__ om, float* __restrict__ aligned)
{
    extern __shared__ float lds[];
    float* sl = lds;             // [72][64]
    float* wl = lds + 72*64;     // [64][76] (ck stride padded to 76)

    int blk = blockIdx.x;        // b(2) y(7) xh(1)
    int xh = blk & 1;
    int y  = (blk >> 1) & 127;
    int b  = blk >> 8;

    int tid = threadIdx.x;
    int px  = tid & 63;          // local x within half-row
    int cs  = tid >> 6;          // 0..3 channel-slot
    int gx  = xh*64 + px;

    int oo = tid & 15;
    int pg = tid >> 4;           // 0..15

    float4 acc0 = make_float4(0.f, 0.f, 0.f, 0.f);
    float4 acc1 = acc0, acc2 = acc0, acc3 = acc0;

    const float* omb = om + ((b*27) << 14) + (y << 7);
    const float* f1b = f1 + ((size_t)(b*CC) << 14);

#pragma unroll 1
    for (int chunk = 0; chunk < 8; ++chunk) {
        // stage weights: wl[o][ck] = mw[o*576 + chunk*72 + ck]
        for (int q = tid; q < 64*18; q += 256) {
            int o = q / 18;
            int ck4 = (q - o*18) * 4;
            float4 wv = *(const float4*)&mw[o*576 + chunk*72 + ck4];
            *(float4*)&wl[o*76 + ck4] = wv;
        }

        // phase A: bilinear sampling, 2 channels per thread.
#pragma unroll 1
        for (int k = 0; k < 9; ++k) {
            float off0 = omb[((2*k)   << 14) + gx];
            float off1 = omb[((2*k+1) << 14) + gx];
            float mk   = omb[((18+k)  << 14) + gx];   // already sigmoided in K1

            float pyf = (float)y  + (float)(k/3) - 1.f + off0;
            float pxg = (float)gx + (float)(k%3) - 1.f + off1;
            float fy = floorf(pyf), fx = floorf(pxg);
            int y0 = (int)fy, x0 = (int)fx;
            float wy = pyf - fy, wx = pxg - fx;
            float oy = 1.f - wy, ox = 1.f - wx;
            float w00 = oy*ox, w01 = oy*wx, w10 = wy*ox, w11 = wy*wx;
            bool yv0 = (unsigned)y0     < (unsigned)HH;
            bool yv1 = (unsigned)(y0+1) < (unsigned)HH;
            bool xv0 = (unsigned)x0     < (unsigned)WW;
            bool xv1 = (unsigned)(x0+1) < (unsigned)WW;
            int i00 = y0*WW + x0;

#pragma unroll
            for (int cl = 0; cl < 2; ++cl) {
                int c_loc = cs*2 + cl;
                int c = chunk*8 + c_loc;
                const float* src = f1b + (c << 14);
                float s = 0.f;
                if (yv0 && xv0) s += w00 * src[i00];
                if (yv0 && xv1) s += w01 * src[i00 + 1];
                if (yv1 && xv0) s += w10 * src[i00 + WW];
                if (yv1 && xv1) s += w11 * src[i00 + WW + 1];
                sl[(c_loc*9 + k)*64 + px] = s * mk;
            }
        }
        __syncthreads();

        // phase B: acc_j += wl[oo+16j][ck..ck+3] * sl[ck..ck+3][pg*4..+3]
        for (int ck = 0; ck < 72; ck += 4) {
            float4 s0 = *(const float4*)&sl[(ck+0)*64 + pg*4];
            float4 s1 = *(const float4*)&sl[(ck+1)*64 + pg*4];
            float4 s2 = *(const float4*)&sl[(ck+2)*64 + pg*4];
            float4 s3 = *(const float4*)&sl[(ck+3)*64 + pg*4];
            float4 w0 = *(const float4*)&wl[(oo +  0)*76 + ck];
            float4 w1 = *(const float4*)&wl[(oo + 16)*76 + ck];
            float4 w2 = *(const float4*)&wl[(oo + 32)*76 + ck];
            float4 w3 = *(const float4*)&wl[(oo + 48)*76 + ck];

            acc0.x += w0.x*s0.x + w0.y*s1.x + w0.z*s2.x + w0.w*s3.x;
            acc0.y += w0.x*s0.y + w0.y*s1.y + w0.z*s2.y + w0.w*s3.y;
            acc0.z += w0.x*s0.z + w0.y*s1.z + w0.z*s2.z + w0.w*s3.z;
            acc0.w += w0.x*s0.w + w0.y*s1.w + w0.z*s2.w + w0.w*s3.w;

            acc1.x += w1.x*s0.x + w1.y*s1.x + w1.z*s2.x + w1.w*s3.x;
            acc1.y += w1.x*s0.y + w1.y*s1.y + w1.z*s2.y + w1.w*s3.y;
            acc1.z += w1.x*s0.z + w1.y*s1.z + w1.z*s2.z + w1.w*s3.z;
            acc1.w += w1.x*s0.w + w1.y*s1.w + w1.z*s2.w + w1.w*s3.w;

            acc2.x += w2.x*s0.x + w2.y*s1.x + w2.z*s2.x + w2.w*s3.x;
            acc2.y += w2.x*s0.y + w2.y*s1.y + w2.z*s2.y + w2.w*s3.y;
            acc2.z += w2.x*s0.z + w2.y*s1.z + w2.z*s2.z + w2.w*s3.z;
            acc2.w += w2.x*s0.w + w2.y*s1.w + w2.z*s2.w + w2.w*s3.w;

            acc3.x += w3.x*s0.x + w3.y*s1.x + w3.z*s2.x + w3.w*s3.x;
            acc3.y += w3.x*s0.y + w3.y*s1.y + w3.z*s2.y + w3.w*s3.y;
            acc3.z += w3.x*s0.z + w3.y*s1.z + w3.z*s2.z + w3.w*s3.z;
            acc3.w += w3.x*s0.w + w3.y*s1.w + w3.z*s2.w + w3.w*s3.w;
        }
        __syncthreads();
    }

    int obase = (b*CC << 14) + (y << 7) + xh*64 + pg*4;
    *(float4*)&aligned[obase + ((oo +  0) << 14)] = acc0;
    *(float4*)&aligned[obase + ((oo + 16) << 14)] = acc1;
    *(float4*)&aligned[obase + ((oo + 32) << 14)] = acc2;
    *(float4*)&aligned[obase + ((oo + 48) << 14)] = acc3;
}

// ---------------- K3: per-channel partial sum / sumsq; grid 128 = (c, batch-half)
__global__ __launch_bounds__(256) void k3_stats(
    const float* __restrict__ a, float* __restrict__ stats)
{
    int c = blockIdx.x & 63;
    int half = blockIdx.x >> 6;
    int tid = threadIdx.x;
    float s = 0.f, s2 = 0.f;
    for (int bimg = half*2; bimg < half*2 + 2; ++bimg) {
        const float* base = a + ((size_t)(bimg*CC + c) << 14);
        for (int i = tid*4; i < HWP; i += 256*4) {
            float4 v = *(const float4*)&base[i];
            s  += v.x + v.y + v.z + v.w;
            s2 += v.x*v.x + v.y*v.y + v.z*v.z + v.w*v.w;
        }
    }
    for (int off = 32; off > 0; off >>= 1) {
        s  += __shfl_down(s,  off, 64);
        s2 += __shfl_down(s2, off, 64);
    }
    __shared__ float rs[4], rs2[4];
    int w = tid >> 6;
    if ((tid & 63) == 0) { rs[w] = s; rs2[w] = s2; }
    __syncthreads();
    if (tid == 0) {
        stats[half*128 + c]      = rs[0] + rs[1] + rs[2] + rs[3];
        stats[half*128 + 64 + c] = rs2[0] + rs2[1] + rs2[2] + rs2[3];
    }
}

// ---------------- K4: in-place normalize + affine (combines the 2 partials)
__global__ __launch_bounds__(256) void k4_norm(
    float* __restrict__ a, const float* __restrict__ stats,
    const float* __restrict__ gamma, const float* __restrict__ beta)
{
    const float invN = 1.f / 65536.f;
    int n4 = (BB*CC*HWP) / 4;
    for (int i4 = blockIdx.x*256 + threadIdx.x; i4 < n4; i4 += gridDim.x*256) {
        int c = (i4 >> 12) & 63;
        float mean = (stats[c] + stats[128 + c]) * invN;
        float var  = (stats[64 + c] + stats[192 + c]) * invN - mean*mean;
        float sc = gamma[c] * rsqrtf(var + 1e-5f);
        float sh = beta[c] - mean*sc;
        float4 v = ((const float4*)a)[i4];
        v.x = v.x*sc + sh; v.y = v.y*sc + sh;
        v.z = v.z*sc + sh; v.w = v.w*sc + sh;
        ((float4*)a)[i4] = v;
    }
}

extern "C" void kernel_launch(void* const* d_in, const int* in_sizes, int n_in,
                              void* d_out, int out_size, void* d_ws, size_t ws_size,
                              hipStream_t stream)
{
    const float* f1    = (const float*)d_in[0];
    const float* f3    = (const float*)d_in[1];
    const float* ow    = (const float*)d_in[2];
    const float* ob    = (const float*)d_in[3];
    const float* mw    = (const float*)d_in[4];
    const float* gamma = (const float*)d_in[5];
    const float* beta  = (const float*)d_in[6];
    float* out = (float*)d_out;

    float* om    = (float*)d_ws;               // [4][27][128][128] = 7,077,888 B
    float* stats = om + 4*27*HWP;              // [256] floats
    float* owt   = stats + 256;                // [3][128][96] = 147,456 B

    const int lds2 = (72*64 + 64*76)*4;        // 37,888 B
    (void)hipFuncSetAttribute((const void*)k2_deform,
        hipFuncAttributeMaxDynamicSharedMemorySize, lds2);

    hipLaunchKernelGGL(k0_wt, dim3(122), dim3(256), 0, stream, ow, owt);
    hipLaunchKernelGGL(k1_offset_conv, dim3(256, 3), dim3(256), 0, stream,
                       f1, f3, owt, ob, om);
    hipLaunchKernelGGL(k2_deform, dim3(1024), dim3(256), lds2, stream,
                       f1, mw, om, out);
    hipLaunchKernelGGL(k3_stats, dim3(128), dim3(256), 0, stream, out, stats);
    hipLaunchKernelGGL(k4_norm, dim3(2048), dim3(256), 0, stream,
                       out, stats, gamma, beta);
}

// Round 7
// 243.304 us; speedup vs baseline: 3.6202x; 1.3491x over previous
//
#include <hip/hip_runtime.h>
#include <math.h>

#define BB 4
#define CC 64
#define HH 128
#define WW 128
#define HWP 16384

typedef _Float16 h2 __attribute__((ext_vector_type(2)));
typedef __fp16  p2 __attribute__((ext_vector_type(2)));   // cvt_pkrtz's return type
union HU { unsigned u; h2 h; p2 p; };
static __device__ __forceinline__ h2 u2h(unsigned x){ HU v; v.u = x; return v.h; }
static __device__ __forceinline__ unsigned h2u(h2 x){ HU v; v.h = x; return v.u; }
static __device__ __forceinline__ unsigned pk2u(float a, float b){
    HU v; v.p = __builtin_amdgcn_cvt_pkrtz(a, b); return v.u;
}

// ---------------- K0: build owt [grp][c][k*9+t] (stride 96) and
// mwt [chunk][pair][o] half2 where pair p = k*4 + cs holds channels
// (chunk*8 + 2*(p&3), +1) at tap k = p>>2.
__global__ __launch_bounds__(256) void k0_wt(
    const float* __restrict__ ow, const float* __restrict__ mw,
    float* __restrict__ owt, unsigned* __restrict__ mwt)
{
    int i = blockIdx.x*256 + threadIdx.x;
    if (i < 27*128*9) {
        int t  = i % 9;
        int r  = i / 9;
        int c  = r % 128;
        int ko = r / 128;                      // 0..26
        int grp = ko / 9, kk = ko % 9;
        owt[(grp*128 + c)*96 + kk*9 + t] = ow[i];
    } else if (i < 27*128*9 + 8*36*64) {
        int j = i - 27*128*9;                  // 0..18431
        int chunk = j / 2304;
        int r = j % 2304;
        int p = r >> 6;                        // 0..35
        int o = r & 63;
        int c0 = chunk*8 + 2*(p & 3);
        int k  = p >> 2;
        float lo = mw[o*576 + c0*9 + k];
        float hi = mw[o*576 + (c0+1)*9 + k];
        mwt[j] = pk2u(lo, hi);
    }
}

// ---------------- K1: 3x3 conv over concat[f1,f3] -> om [B][27][H][W]
// No LDS. Weights via wave-uniform indices -> scalar loads.
// Group 2 (channels 18..26) gets sigmoid applied (mask).
__global__ __launch_bounds__(256) void k1_offset_conv(
    const float* __restrict__ f1, const float* __restrict__ f3,
    const float* __restrict__ owt, const float* __restrict__ ob,
    float* __restrict__ om)
{
    int grp = blockIdx.y;          // 0..2
    int pix = blockIdx.x*256 + threadIdx.x;
    int b = pix >> 14;
    int y = (pix >> 7) & 127;
    int x = pix & 127;

    int   toff[9];
    float tval[9];
#pragma unroll
    for (int t = 0; t < 9; ++t) {
        int yy = y + t/3 - 1;
        int xx = x + (t % 3) - 1;
        bool ok = ((unsigned)yy < (unsigned)HH) && ((unsigned)xx < (unsigned)WW);
        tval[t] = ok ? 1.f : 0.f;
        toff[t] = ok ? (yy*WW + xx) : 0;
    }

    float acc[9];
#pragma unroll
    for (int k = 0; k < 9; ++k) acc[k] = ob[grp*9 + k];

    const float* base0 = f1 + ((size_t)(b*CC) << 14);
    const float* base1 = f3 + ((size_t)(b*CC) << 14);
    const float* wgs = owt + grp*128*96;       // uniform base

    for (int half = 0; half < 2; ++half) {
        const float* srcb = (half == 0) ? base0 : base1;
        for (int c0 = 0; c0 < 64; ++c0) {
            const float* src = srcb + (c0 << 14);
            float v[9];
#pragma unroll
            for (int t = 0; t < 9; ++t) v[t] = tval[t] * src[toff[t]];
            const float* wr = wgs + (half*64 + c0)*96;   // uniform
#pragma unroll
            for (int k = 0; k < 9; ++k)
#pragma unroll
                for (int t = 0; t < 9; ++t)
                    acc[k] = fmaf(v[t], wr[k*9 + t], acc[k]);
        }
    }

    int obase = ((b*27 + grp*9) << 14) + (y << 7) + x;
#pragma unroll
    for (int k = 0; k < 9; ++k) {
        float a = acc[k];
        if (grp == 2) a = 1.f / (1.f + __expf(-a));   // sigmoid for mask group
        om[obase + (k << 14)] = a;
    }
}

// ---------------- K2: deformable conv (f16 dot2 GEMM core)
// block = half-row (64 px), grid 1024; 8 chunks of 8 input channels.
// LDS: sl2[36][64] u32 + wl2[36][64] u32 + params 1728 u32 = 25344 B.
// Params (addr+dx/dy bits, 4 premasked*mask-scaled f16 weights) computed once.
__global__ __launch_bounds__(256) void k2_deform(
    const float* __restrict__ f1, const unsigned* __restrict__ mwt,
    const float* __restrict__ om, float* __restrict__ aligned)
{
    extern __shared__ unsigned lds[];
    unsigned* sl2  = lds;             // [36][64] half2 samples (pair-major)
    unsigned* wl2  = lds + 2304;      // [36][64] half2 weights
    unsigned* pl_a = lds + 4608;      // [9][64] addr|dx<<14|dy<<15
    unsigned* pl_w01 = pl_a + 576;    // [9][64] half2(w00,w01)
    unsigned* pl_w23 = pl_w01 + 576;  // [9][64] half2(w10,w11)

    int blk = blockIdx.x;        // b(2) y(7) xh(1)
    int xh = blk & 1;
    int y  = (blk >> 1) & 127;
    int b  = blk >> 8;

    int tid = threadIdx.x;
    int px  = tid & 63;          // local x within half-row
    int cs  = tid >> 6;          // 0..3 channel-slot
    int oo  = tid & 15;
    int pg  = tid >> 4;          // 0..15

    const float* omb = om + ((b*27) << 14) + (y << 7);
    const float* f1b = f1 + ((size_t)(b*CC) << 14);

    // ---- param pre-phase: 576 items (k, px)
    for (int i = tid; i < 576; i += 256) {
        int k = i >> 6, lpx = i & 63;
        int gxp = xh*64 + lpx;
        float off0 = omb[((2*k)   << 14) + gxp];
        float off1 = omb[((2*k+1) << 14) + gxp];
        float mk   = omb[((18+k)  << 14) + gxp];   // sigmoided in K1

        float pyf = (float)y   + (float)(k/3) - 1.f + off0;
        float pxg = (float)gxp + (float)(k%3) - 1.f + off1;
        float fy = floorf(pyf), fx = floorf(pxg);
        int y0 = (int)fy, x0 = (int)fx;
        float wy = pyf - fy, wx = pxg - fx;
        float oy = 1.f - wy, ox = 1.f - wx;
        bool yv0 = (unsigned)y0     < (unsigned)HH;
        bool yv1 = (unsigned)(y0+1) < (unsigned)HH;
        bool xv0 = (unsigned)x0     < (unsigned)WW;
        bool xv1 = (unsigned)(x0+1) < (unsigned)WW;
        int y0c = min(max(y0, 0), 127);
        int x0c = min(max(x0, 0), 127);
        int y1c = min(max(y0+1, 0), 127);
        int x1c = min(max(x0+1, 0), 127);
        int dy = y1c - y0c;                  // 0 or 1
        int dx = x1c - x0c;                  // 0 or 1
        unsigned a = (unsigned)((y0c << 7) + x0c) | ((unsigned)dx << 14) | ((unsigned)dy << 15);
        float w00 = (yv0 && xv0) ? oy*ox*mk : 0.f;
        float w01 = (yv0 && xv1) ? oy*wx*mk : 0.f;
        float w10 = (yv1 && xv0) ? wy*ox*mk : 0.f;
        float w11 = (yv1 && xv1) ? wy*wx*mk : 0.f;
        pl_a[i]   = a;
        pl_w01[i] = pk2u(w00, w01);
        pl_w23[i] = pk2u(w10, w11);
    }
    __syncthreads();

    float4 acc0 = make_float4(0.f,0.f,0.f,0.f);
    float4 acc1 = acc0, acc2 = acc0, acc3 = acc0;

#pragma unroll 1
    for (int chunk = 0; chunk < 8; ++chunk) {
        // stage weights: linear copy of 2304 u32 from mwt
        const unsigned* wsrc = mwt + chunk*2304;
        for (int q = tid; q < 2304; q += 256) wl2[q] = wsrc[q];

        // phase A: sampling, 2 channels (cs*2, cs*2+1) per thread per k
        const float* s0p = f1b + ((chunk*8 + cs*2) << 14);
        const float* s1p = s0p + (1 << 14);
#pragma unroll 3
        for (int k = 0; k < 9; ++k) {
            unsigned a   = pl_a[k*64 + px];
            h2 hw01 = u2h(pl_w01[k*64 + px]);
            h2 hw23 = u2h(pl_w23[k*64 + px]);
            int i00 = (int)(a & 0x3FFFu);
            int dx  = (int)((a >> 14) & 1u);
            int dyo = (int)((a >> 15) & 1u) << 7;
            float w00 = (float)hw01.x, w01 = (float)hw01.y;
            float w10 = (float)hw23.x, w11 = (float)hw23.y;
            int i10 = i00 + dyo;

            float sa = w00*s0p[i00] + w01*s0p[i00+dx] + w10*s0p[i10] + w11*s0p[i10+dx];
            float sb = w00*s1p[i00] + w01*s1p[i00+dx] + w10*s1p[i10] + w11*s1p[i10+dx];
            sl2[(k*4 + cs)*64 + px] = pk2u(sa, sb);
        }
        __syncthreads();

        // phase B: acc[j][i] += dot2(w[p][oo+16j], s[p][pg*4+i])
#pragma unroll 4
        for (int p = 0; p < 36; ++p) {
            uint4 sv = *(const uint4*)&sl2[p*64 + pg*4];
            unsigned w0 = wl2[p*64 + oo];
            unsigned w1 = wl2[p*64 + oo + 16];
            unsigned w2 = wl2[p*64 + oo + 32];
            unsigned w3 = wl2[p*64 + oo + 48];
            h2 s0 = u2h(sv.x), s1 = u2h(sv.y), s2 = u2h(sv.z), s3 = u2h(sv.w);
            h2 hw0 = u2h(w0), hw1 = u2h(w1), hw2 = u2h(w2), hw3 = u2h(w3);
            acc0.x = __builtin_amdgcn_fdot2(hw0, s0, acc0.x, false);
            acc0.y = __builtin_amdgcn_fdot2(hw0, s1, acc0.y, false);
            acc0.z = __builtin_amdgcn_fdot2(hw0, s2, acc0.z, false);
            acc0.w = __builtin_amdgcn_fdot2(hw0, s3, acc0.w, false);
            acc1.x = __builtin_amdgcn_fdot2(hw1, s0, acc1.x, false);
            acc1.y = __builtin_amdgcn_fdot2(hw1, s1, acc1.y, false);
            acc1.z = __builtin_amdgcn_fdot2(hw1, s2, acc1.z, false);
            acc1.w = __builtin_amdgcn_fdot2(hw1, s3, acc1.w, false);
            acc2.x = __builtin_amdgcn_fdot2(hw2, s0, acc2.x, false);
            acc2.y = __builtin_amdgcn_fdot2(hw2, s1, acc2.y, false);
            acc2.z = __builtin_amdgcn_fdot2(hw2, s2, acc2.z, false);
            acc2.w = __builtin_amdgcn_fdot2(hw2, s3, acc2.w, false);
            acc3.x = __builtin_amdgcn_fdot2(hw3, s0, acc3.x, false);
            acc3.y = __builtin_amdgcn_fdot2(hw3, s1, acc3.y, false);
            acc3.z = __builtin_amdgcn_fdot2(hw3, s2, acc3.z, false);
            acc3.w = __builtin_amdgcn_fdot2(hw3, s3, acc3.w, false);
        }
        __syncthreads();
    }

    int obase = (b*CC << 14) + (y << 7) + xh*64 + pg*4;
    *(float4*)&aligned[obase + ((oo +  0) << 14)] = acc0;
    *(float4*)&aligned[obase + ((oo + 16) << 14)] = acc1;
    *(float4*)&aligned[obase + ((oo + 32) << 14)] = acc2;
    *(float4*)&aligned[obase + ((oo + 48) << 14)] = acc3;
}

// ---------------- K3: per-channel partial sum / sumsq; grid 256 = (c, bimg)
__global__ __launch_bounds__(256) void k3_stats(
    const float* __restrict__ a, float* __restrict__ stats)
{
    int c = blockIdx.x & 63;
    int bimg = blockIdx.x >> 6;
    int tid = threadIdx.x;
    float s = 0.f, s2 = 0.f;
    const float* base = a + ((size_t)(bimg*CC + c) << 14);
    for (int i = tid*4; i < HWP; i += 256*4) {
        float4 v = *(const float4*)&base[i];
        s  += v.x + v.y + v.z + v.w;
        s2 += v.x*v.x + v.y*v.y + v.z*v.z + v.w*v.w;
    }
    for (int off = 32; off > 0; off >>= 1) {
        s  += __shfl_down(s,  off, 64);
        s2 += __shfl_down(s2, off, 64);
    }
    __shared__ float rs[4], rs2[4];
    int w = tid >> 6;
    if ((tid & 63) == 0) { rs[w] = s; rs2[w] = s2; }
    __syncthreads();
    if (tid == 0) {
        stats[bimg*128 + c]      = rs[0] + rs[1] + rs[2] + rs[3];
        stats[bimg*128 + 64 + c] = rs2[0] + rs2[1] + rs2[2] + rs2[3];
    }
}

// ---------------- K4: in-place normalize + affine (combines 4 partials)
__global__ __launch_bounds__(256) void k4_norm(
    float* __restrict__ a, const float* __restrict__ stats,
    const float* __restrict__ gamma, const float* __restrict__ beta)
{
    const float invN = 1.f / 65536.f;
    int n4 = (BB*CC*HWP) / 4;
    for (int i4 = blockIdx.x*256 + threadIdx.x; i4 < n4; i4 += gridDim.x*256) {
        int c = (i4 >> 12) & 63;
        float sm  = stats[c] + stats[128+c] + stats[256+c] + stats[384+c];
        float sq  = stats[64+c] + stats[192+c] + stats[320+c] + stats[448+c];
        float mean = sm * invN;
        float var  = sq * invN - mean*mean;
        float sc = gamma[c] * rsqrtf(var + 1e-5f);
        float sh = beta[c] - mean*sc;
        float4 v = ((const float4*)a)[i4];
        v.x = v.x*sc + sh; v.y = v.y*sc + sh;
        v.z = v.z*sc + sh; v.w = v.w*sc + sh;
        ((float4*)a)[i4] = v;
    }
}

extern "C" void kernel_launch(void* const* d_in, const int* in_sizes, int n_in,
                              void* d_out, int out_size, void* d_ws, size_t ws_size,
                              hipStream_t stream)
{
    const float* f1    = (const float*)d_in[0];
    const float* f3    = (const float*)d_in[1];
    const float* ow    = (const float*)d_in[2];
    const float* ob    = (const float*)d_in[3];
    const float* mw    = (const float*)d_in[4];
    const float* gamma = (const float*)d_in[5];
    const float* beta  = (const float*)d_in[6];
    float* out = (float*)d_out;

    float* om    = (float*)d_ws;               // [4][27][128][128] = 7,077,888 B
    float* stats = om + 4*27*HWP;              // [512] floats
    float* owt   = stats + 512;                // [3][128][96] = 147,456 B
    unsigned* mwt = (unsigned*)(owt + 3*128*96);  // [8][36][64] u32 = 73,728 B

    const int lds2 = (2304 + 2304 + 3*576) * 4;   // 25,344 B
    (void)hipFuncSetAttribute((const void*)k2_deform,
        hipFuncAttributeMaxDynamicSharedMemorySize, lds2);

    hipLaunchKernelGGL(k0_wt, dim3(194), dim3(256), 0, stream, ow, mw, owt, mwt);
    hipLaunchKernelGGL(k1_offset_conv, dim3(256, 3), dim3(256), 0, stream,
                       f1, f3, owt, ob, om);
    hipLaunchKernelGGL(k2_deform, dim3(1024), dim3(256), lds2, stream,
                       f1, mwt, om, out);
    hipLaunchKernelGGL(k3_stats, dim3(256), dim3(256), 0, stream, out, stats);
    hipLaunchKernelGGL(k4_norm, dim3(2048), dim3(256), 0, stream,
                       out, stats, gamma, beta);
}

// Round 8
// 199.129 us; speedup vs baseline: 4.4234x; 1.2218x over previous
//
#include <hip/hip_runtime.h>
#include <math.h>

#define BB 4
#define CC 64
#define HH 128
#define WW 128
#define HWP 16384

typedef _Float16 h2 __attribute__((ext_vector_type(2)));
typedef __fp16  p2 __attribute__((ext_vector_type(2)));   // cvt_pkrtz's return type
union HU { unsigned u; h2 h; p2 p; };
static __device__ __forceinline__ h2 u2h(unsigned x){ HU v; v.u = x; return v.h; }
static __device__ __forceinline__ unsigned pk2u(float a, float b){
    HU v; v.p = __builtin_amdgcn_cvt_pkrtz(a, b); return v.u;
}

// ---------------- K0: pack weights.
// owt2 [grp][cp][k*9+t] (u32 half2, stride 96): offset-conv weights, channel
//   pair cp -> concat channels (2cp, 2cp+1).
// mwt  [chunk][pair][o] (u32 half2): deform-conv weights, pair p = k*4+cs ->
//   channels (chunk*8 + 2*(p&3), +1) at tap k = p>>2.
__global__ __launch_bounds__(256) void k0_wt(
    const float* __restrict__ ow, const float* __restrict__ mw,
    unsigned* __restrict__ owt2, unsigned* __restrict__ mwt)
{
    int i = blockIdx.x*256 + threadIdx.x;
    if (i < 15552) {                           // 3*64*81
        int cpl = i / 81;                      // grp*64 + cp
        int r   = i % 81;                      // k*9 + t
        int k = r / 9, t = r % 9;
        int grp = cpl >> 6, cp = cpl & 63;
        int o = grp*9 + k;
        int c0 = cp*2;
        float lo = ow[(o*128 + c0    )*9 + t];
        float hi = ow[(o*128 + c0 + 1)*9 + t];
        owt2[cpl*96 + r] = pk2u(lo, hi);
    } else if (i < 15552 + 18432) {            // 8*36*64
        int j = i - 15552;
        int chunk = j / 2304;
        int r = j % 2304;
        int p = r >> 6;                        // 0..35
        int o = r & 63;
        int c0 = chunk*8 + 2*(p & 3);
        int k  = p >> 2;
        float lo = mw[o*576 + c0*9 + k];
        float hi = mw[o*576 + (c0+1)*9 + k];
        mwt[j] = pk2u(lo, hi);
    }
}

// ---------------- K1: 3x3 conv over concat[f1,f3] -> om [B][27][H][W]
// f16-dot2 core: channel pairs packed to half2, weights via wave-uniform
// s_loads. Group 2 (channels 18..26) gets sigmoid applied (mask).
__global__ __launch_bounds__(256) void k1_offset_conv(
    const float* __restrict__ f1, const float* __restrict__ f3,
    const unsigned* __restrict__ owt2, const float* __restrict__ ob,
    float* __restrict__ om)
{
    int grp = blockIdx.y;          // 0..2
    int pix = blockIdx.x*256 + threadIdx.x;
    int b = pix >> 14;
    int y = (pix >> 7) & 127;
    int x = pix & 127;

    int   toff[9];
    float tval[9];
#pragma unroll
    for (int t = 0; t < 9; ++t) {
        int yy = y + t/3 - 1;
        int xx = x + (t % 3) - 1;
        bool ok = ((unsigned)yy < (unsigned)HH) && ((unsigned)xx < (unsigned)WW);
        tval[t] = ok ? 1.f : 0.f;
        toff[t] = ok ? (yy*WW + xx) : 0;
    }

    float acc[9];
#pragma unroll
    for (int k = 0; k < 9; ++k) acc[k] = ob[grp*9 + k];

    const float* base0 = f1 + ((size_t)(b*CC) << 14);
    const float* base1 = f3 + ((size_t)(b*CC) << 14);
    const unsigned* wgs = owt2 + grp*64*96;    // uniform base

    for (int half = 0; half < 2; ++half) {
        const float* srcb = (half == 0) ? base0 : base1;
        for (int cph = 0; cph < 32; ++cph) {
            const float* srcA = srcb + ((cph*2) << 14);
            const float* srcB = srcA + (1 << 14);
            h2 v[9];
#pragma unroll
            for (int t = 0; t < 9; ++t) {
                float va = tval[t] * srcA[toff[t]];
                float vb = tval[t] * srcB[toff[t]];
                v[t] = u2h(pk2u(va, vb));
            }
            const unsigned* wr = wgs + (half*32 + cph)*96;   // uniform
#pragma unroll
            for (int k = 0; k < 9; ++k)
#pragma unroll
                for (int t = 0; t < 9; ++t)
                    acc[k] = __builtin_amdgcn_fdot2(u2h(wr[k*9 + t]), v[t], acc[k], false);
        }
    }

    int obase = ((b*27 + grp*9) << 14) + (y << 7) + x;
#pragma unroll
    for (int k = 0; k < 9; ++k) {
        float a = acc[k];
        if (grp == 2) a = 1.f / (1.f + __expf(-a));   // sigmoid for mask group
        om[obase + (k << 14)] = a;
    }
}

// ---------------- K2: deformable conv (f16 dot2 GEMM core)
// block = quarter-row (32 px), grid 2048 -> 8 blocks/CU; 8 chunks of 8 ch.
// LDS: sl2[36][32] + wl2[36][64] + params [9][32]*3 = 17280 B.
__global__ __launch_bounds__(256) void k2_deform(
    const float* __restrict__ f1, const unsigned* __restrict__ mwt,
    const float* __restrict__ om, float* __restrict__ aligned)
{
    extern __shared__ unsigned lds[];
    unsigned* sl2  = lds;             // [36][32] half2 samples (pair-major)
    unsigned* wl2  = lds + 1152;      // [36][64] half2 weights
    unsigned* pl_a = lds + 3456;      // [9][32] addr|dx<<14|dy<<15
    unsigned* pl_w01 = pl_a + 288;    // [9][32] half2(w00,w01)
    unsigned* pl_w23 = pl_w01 + 288;  // [9][32] half2(w10,w11)

    int blk = blockIdx.x;        // b(2) y(7) xq(2)
    int xq = blk & 3;
    int y  = (blk >> 2) & 127;
    int b  = blk >> 9;

    int tid = threadIdx.x;
    int oo  = tid & 31;          // output channel low 5 bits
    int pg  = tid >> 5;          // 0..7 pixel group

    const float* omb = om + ((b*27) << 14) + (y << 7);
    const float* f1b = f1 + ((size_t)(b*CC) << 14);

    // ---- param pre-phase: 288 items (k, px)
    for (int i = tid; i < 288; i += 256) {
        int k = i >> 5, lpx = i & 31;
        int gxp = xq*32 + lpx;
        float off0 = omb[((2*k)   << 14) + gxp];
        float off1 = omb[((2*k+1) << 14) + gxp];
        float mk   = omb[((18+k)  << 14) + gxp];   // sigmoided in K1

        float pyf = (float)y   + (float)(k/3) - 1.f + off0;
        float pxg = (float)gxp + (float)(k%3) - 1.f + off1;
        float fy = floorf(pyf), fx = floorf(pxg);
        int y0 = (int)fy, x0 = (int)fx;
        float wy = pyf - fy, wx = pxg - fx;
        float oy = 1.f - wy, ox = 1.f - wx;
        bool yv0 = (unsigned)y0     < (unsigned)HH;
        bool yv1 = (unsigned)(y0+1) < (unsigned)HH;
        bool xv0 = (unsigned)x0     < (unsigned)WW;
        bool xv1 = (unsigned)(x0+1) < (unsigned)WW;
        int y0c = min(max(y0, 0), 127);
        int x0c = min(max(x0, 0), 127);
        int dy = min(max(y0+1, 0), 127) - y0c;   // 0 or 1
        int dx = min(max(x0+1, 0), 127) - x0c;   // 0 or 1
        unsigned a = (unsigned)((y0c << 7) + x0c) | ((unsigned)dx << 14) | ((unsigned)dy << 15);
        float w00 = (yv0 && xv0) ? oy*ox*mk : 0.f;
        float w01 = (yv0 && xv1) ? oy*wx*mk : 0.f;
        float w10 = (yv1 && xv0) ? wy*ox*mk : 0.f;
        float w11 = (yv1 && xv1) ? wy*wx*mk : 0.f;
        pl_a[i]   = a;
        pl_w01[i] = pk2u(w00, w01);
        pl_w23[i] = pk2u(w10, w11);
    }
    __syncthreads();

    float4 acc0 = make_float4(0.f,0.f,0.f,0.f);
    float4 acc1 = acc0;

#pragma unroll 1
    for (int chunk = 0; chunk < 8; ++chunk) {
        // stage weights: linear copy of 2304 u32 from mwt
        const unsigned* wsrc = mwt + chunk*2304;
        for (int q = tid; q < 2304; q += 256) wl2[q] = wsrc[q];

        // phase A: 1152 items (pair p, px)
#pragma unroll 1
        for (int i = tid; i < 1152; i += 256) {
            int p = i >> 5, lpx = i & 31;
            int k = p >> 2, cslot = p & 3;
            unsigned a   = pl_a[k*32 + lpx];
            h2 hw01 = u2h(pl_w01[k*32 + lpx]);
            h2 hw23 = u2h(pl_w23[k*32 + lpx]);
            int i00 = (int)(a & 0x3FFFu);
            int dx  = (int)((a >> 14) & 1u);
            int dyo = (int)((a >> 15) & 1u) << 7;
            float w00 = (float)hw01.x, w01 = (float)hw01.y;
            float w10 = (float)hw23.x, w11 = (float)hw23.y;
            int i10 = i00 + dyo;

            const float* s0p = f1b + ((chunk*8 + 2*cslot) << 14);
            const float* s1p = s0p + (1 << 14);
            float sa = w00*s0p[i00] + w01*s0p[i00+dx] + w10*s0p[i10] + w11*s0p[i10+dx];
            float sb = w00*s1p[i00] + w01*s1p[i00+dx] + w10*s1p[i10] + w11*s1p[i10+dx];
            sl2[p*32 + lpx] = pk2u(sa, sb);
        }
        __syncthreads();

        // phase B: acc[j][i] += dot2(w[p][oo+32j], s[p][pg*4+i])
#pragma unroll 4
        for (int p = 0; p < 36; ++p) {
            uint4 sv = *(const uint4*)&sl2[p*32 + pg*4];
            unsigned w0 = wl2[p*64 + oo];
            unsigned w1 = wl2[p*64 + oo + 32];
            h2 s0 = u2h(sv.x), s1 = u2h(sv.y), s2 = u2h(sv.z), s3 = u2h(sv.w);
            h2 hw0 = u2h(w0), hw1 = u2h(w1);
            acc0.x = __builtin_amdgcn_fdot2(hw0, s0, acc0.x, false);
            acc0.y = __builtin_amdgcn_fdot2(hw0, s1, acc0.y, false);
            acc0.z = __builtin_amdgcn_fdot2(hw0, s2, acc0.z, false);
            acc0.w = __builtin_amdgcn_fdot2(hw0, s3, acc0.w, false);
            acc1.x = __builtin_amdgcn_fdot2(hw1, s0, acc1.x, false);
            acc1.y = __builtin_amdgcn_fdot2(hw1, s1, acc1.y, false);
            acc1.z = __builtin_amdgcn_fdot2(hw1, s2, acc1.z, false);
            acc1.w = __builtin_amdgcn_fdot2(hw1, s3, acc1.w, false);
        }
        __syncthreads();
    }

    int obase = ((b*CC) << 14) + (y << 7) + xq*32 + pg*4;
    *(float4*)&aligned[obase + ((oo     ) << 14)] = acc0;
    *(float4*)&aligned[obase + ((oo + 32) << 14)] = acc1;
}

// ---------------- K3: per-channel partial sum / sumsq; grid 256 = (c, bimg)
__global__ __launch_bounds__(256) void k3_stats(
    const float* __restrict__ a, float* __restrict__ stats)
{
    int c = blockIdx.x & 63;
    int bimg = blockIdx.x >> 6;
    int tid = threadIdx.x;
    float s = 0.f, s2 = 0.f;
    const float* base = a + ((size_t)(bimg*CC + c) << 14);
    for (int i = tid*4; i < HWP; i += 256*4) {
        float4 v = *(const float4*)&base[i];
        s  += v.x + v.y + v.z + v.w;
        s2 += v.x*v.x + v.y*v.y + v.z*v.z + v.w*v.w;
    }
    for (int off = 32; off > 0; off >>= 1) {
        s  += __shfl_down(s,  off, 64);
        s2 += __shfl_down(s2, off, 64);
    }
    __shared__ float rs[4], rs2[4];
    int w = tid >> 6;
    if ((tid & 63) == 0) { rs[w] = s; rs2[w] = s2; }
    __syncthreads();
    if (tid == 0) {
        stats[bimg*128 + c]      = rs[0] + rs[1] + rs[2] + rs[3];
        stats[bimg*128 + 64 + c] = rs2[0] + rs2[1] + rs2[2] + rs2[3];
    }
}

// ---------------- K4: in-place normalize + affine (combines 4 partials)
__global__ __launch_bounds__(256) void k4_norm(
    float* __restrict__ a, const float* __restrict__ stats,
    const float* __restrict__ gamma, const float* __restrict__ beta)
{
    const float invN = 1.f / 65536.f;
    int n4 = (BB*CC*HWP) / 4;
    for (int i4 = blockIdx.x*256 + threadIdx.x; i4 < n4; i4 += gridDim.x*256) {
        int c = (i4 >> 12) & 63;
        float sm  = stats[c] + stats[128+c] + stats[256+c] + stats[384+c];
        float sq  = stats[64+c] + stats[192+c] + stats[320+c] + stats[448+c];
        float mean = sm * invN;
        float var  = sq * invN - mean*mean;
        float sc = gamma[c] * rsqrtf(var + 1e-5f);
        float sh = beta[c] - mean*sc;
        float4 v = ((const float4*)a)[i4];
        v.x = v.x*sc + sh; v.y = v.y*sc + sh;
        v.z = v.z*sc + sh; v.w = v.w*sc + sh;
        ((float4*)a)[i4] = v;
    }
}

extern "C" void kernel_launch(void* const* d_in, const int* in_sizes, int n_in,
                              void* d_out, int out_size, void* d_ws, size_t ws_size,
                              hipStream_t stream)
{
    const float* f1    = (const float*)d_in[0];
    const float* f3    = (const float*)d_in[1];
    const float* ow    = (const float*)d_in[2];
    const float* ob    = (const float*)d_in[3];
    const float* mw    = (const float*)d_in[4];
    const float* gamma = (const float*)d_in[5];
    const float* beta  = (const float*)d_in[6];
    float* out = (float*)d_out;

    float* om    = (float*)d_ws;                  // [4][27][128][128] = 7,077,888 B
    float* stats = om + 4*27*HWP;                 // [512] floats
    unsigned* owt2 = (unsigned*)(stats + 512);    // [3][64][96] u32 = 73,728 B
    unsigned* mwt  = owt2 + 3*64*96;              // [8][36][64] u32 = 73,728 B

    const int lds2 = (1152 + 2304 + 3*288) * 4;   // 17,280 B -> 8 blocks/CU
    (void)hipFuncSetAttribute((const void*)k2_deform,
        hipFuncAttributeMaxDynamicSharedMemorySize, lds2);

    hipLaunchKernelGGL(k0_wt, dim3(133), dim3(256), 0, stream, ow, mw, owt2, mwt);
    hipLaunchKernelGGL(k1_offset_conv, dim3(256, 3), dim3(256), 0, stream,
                       f1, f3, owt2, ob, om);
    hipLaunchKernelGGL(k2_deform, dim3(2048), dim3(256), lds2, stream,
                       f1, mwt, om, out);
    hipLaunchKernelGGL(k3_stats, dim3(256), dim3(256), 0, stream, out, stats);
    hipLaunchKernelGGL(k4_norm, dim3(2048), dim3(256), 0, stream,
                       out, stats, gamma, beta);
}

// Round 9
// 190.134 us; speedup vs baseline: 4.6326x; 1.0473x over previous
//
#include <hip/hip_runtime.h>
#include <math.h>

#define BB 4
#define CC 64
#define HH 128
#define WW 128
#define HWP 16384

typedef _Float16 h2 __attribute__((ext_vector_type(2)));
typedef _Float16 h4 __attribute__((ext_vector_type(4)));
typedef __fp16  p2 __attribute__((ext_vector_type(2)));   // cvt_pkrtz's return type
typedef float f32x4 __attribute__((ext_vector_type(4)));
union HU { unsigned u; h2 h; p2 p; };
union U2H { uint2 u; h4 h; };
static __device__ __forceinline__ h2 u2h(unsigned x){ HU v; v.u = x; return v.h; }
static __device__ __forceinline__ unsigned pk2u(float a, float b){
    HU v; v.p = __builtin_amdgcn_cvt_pkrtz(a, b); return v.u;
}

// ---------------- K0: pack weights.
// owt2 [grp][cp][k*9+t] (u32 half2, stride 96): offset-conv weights (for K1).
// wmf: deform-conv weights as MFMA A-fragments for v_mfma_f32_16x16x16_f16.
//   u32 index ((r*64 + l)*36 + kb)*2 + j holds halves A[r*16 + (l&15)][kappa],
//   kappa = kb*16 + (l>>4)*4 + 2j + {0,1};  kappa -> pair P = kappa/2,
//   P = cp*9 + ktap, channels (2cp, 2cp+1) at tap ktap.
__global__ __launch_bounds__(256) void k0_wt(
    const float* __restrict__ ow, const float* __restrict__ mw,
    unsigned* __restrict__ owt2, unsigned* __restrict__ wmf)
{
    int i = blockIdx.x*256 + threadIdx.x;
    if (i < 15552) {                           // 3*64*81
        int cpl = i / 81;                      // grp*64 + cp
        int r   = i % 81;                      // k*9 + t
        int k = r / 9, t = r % 9;
        int grp = cpl >> 6, cp = cpl & 63;
        int o = grp*9 + k;
        int c0 = cp*2;
        float lo = ow[(o*128 + c0    )*9 + t];
        float hi = ow[(o*128 + c0 + 1)*9 + t];
        owt2[cpl*96 + r] = pk2u(lo, hi);
    } else if (i < 15552 + 18432) {            // wmf: 4*64*36*2
        int idx = i - 15552;
        int j   = idx & 1;
        int t   = idx >> 1;                    // 0..9215
        int kb  = t % 36;
        int rl  = t / 36;                      // 0..255
        int l   = rl & 63;
        int r   = rl >> 6;
        int row = l & 15, ksel = l >> 4;
        int och = r*16 + row;
        int P   = kb*8 + ksel*2 + j;           // pair index 0..287
        int cp  = P / 9;
        int kt  = P - cp*9;
        float lo = mw[och*576 + (2*cp    )*9 + kt];
        float hi = mw[och*576 + (2*cp + 1)*9 + kt];
        wmf[idx] = pk2u(lo, hi);
    }
}

// ---------------- K1: 3x3 conv over concat[f1,f3] -> om [B][27][H][W]
// f16-dot2 core: channel pairs packed to half2, weights via wave-uniform
// s_loads. Group 2 (channels 18..26) gets sigmoid applied (mask).
__global__ __launch_bounds__(256) void k1_offset_conv(
    const float* __restrict__ f1, const float* __restrict__ f3,
    const unsigned* __restrict__ owt2, const float* __restrict__ ob,
    float* __restrict__ om)
{
    int grp = blockIdx.y;          // 0..2
    int pix = blockIdx.x*256 + threadIdx.x;
    int b = pix >> 14;
    int y = (pix >> 7) & 127;
    int x = pix & 127;

    int   toff[9];
    float tval[9];
#pragma unroll
    for (int t = 0; t < 9; ++t) {
        int yy = y + t/3 - 1;
        int xx = x + (t % 3) - 1;
        bool ok = ((unsigned)yy < (unsigned)HH) && ((unsigned)xx < (unsigned)WW);
        tval[t] = ok ? 1.f : 0.f;
        toff[t] = ok ? (yy*WW + xx) : 0;
    }

    float acc[9];
#pragma unroll
    for (int k = 0; k < 9; ++k) acc[k] = ob[grp*9 + k];

    const float* base0 = f1 + ((size_t)(b*CC) << 14);
    const float* base1 = f3 + ((size_t)(b*CC) << 14);
    const unsigned* wgs = owt2 + grp*64*96;    // uniform base

    for (int half = 0; half < 2; ++half) {
        const float* srcb = (half == 0) ? base0 : base1;
        for (int cph = 0; cph < 32; ++cph) {
            const float* srcA = srcb + ((cph*2) << 14);
            const float* srcB = srcA + (1 << 14);
            h2 v[9];
#pragma unroll
            for (int t = 0; t < 9; ++t) {
                float va = tval[t] * srcA[toff[t]];
                float vb = tval[t] * srcB[toff[t]];
                v[t] = u2h(pk2u(va, vb));
            }
            const unsigned* wr = wgs + (half*32 + cph)*96;   // uniform
#pragma unroll
            for (int k = 0; k < 9; ++k)
#pragma unroll
                for (int t = 0; t < 9; ++t)
                    acc[k] = __builtin_amdgcn_fdot2(u2h(wr[k*9 + t]), v[t], acc[k], false);
        }
    }

    int obase = ((b*27 + grp*9) << 14) + (y << 7) + x;
#pragma unroll
    for (int k = 0; k < 9; ++k) {
        float a = acc[k];
        if (grp == 2) a = 1.f / (1.f + __expf(-a));   // sigmoid for mask group
        om[obase + (k << 14)] = a;
    }
}

// ---------------- K2: deformable conv, MFMA phase B.
// block = quarter-row (32 px), 4 waves; grid 2048.
// Wave wv owns out-tile [wv*16, wv*16+16) x both 16-px tiles.
// K = 576 as 2 chunks of 288 (16 channels... 32 channels = 144 pairs each).
// LDS: params 864 u32 + sl[32 px][146 pad] = 22,144 B.
__global__ __launch_bounds__(256) void k2_deform(
    const float* __restrict__ f1, const unsigned* __restrict__ wmf,
    const float* __restrict__ om, float* __restrict__ aligned)
{
    extern __shared__ unsigned lds[];
    unsigned* pl_a   = lds;            // [9][32] addr|dx<<14|dy<<15
    unsigned* pl_w01 = lds + 288;      // [9][32] half2(w00,w01)
    unsigned* pl_w23 = lds + 576;      // [9][32] half2(w10,w11)
    unsigned* sl     = lds + 864;      // [32][146] half2 samples, pad->bank spread

    int blk = blockIdx.x;        // b(2) y(7) xq(2)
    int xq = blk & 3;
    int y  = (blk >> 2) & 127;
    int b  = blk >> 9;

    int tid  = threadIdx.x;
    int lane = tid & 63;
    int wv   = tid >> 6;         // wave id = out-tile index r
    int row  = lane & 15;
    int ksel = lane >> 4;

    const float* omb = om + ((b*27) << 14) + (y << 7);
    const float* f1b = f1 + ((size_t)(b*CC) << 14);

    // ---- param pre-phase: 288 items (k, px)
    for (int i = tid; i < 288; i += 256) {
        int k = i >> 5, lpx = i & 31;
        int gxp = xq*32 + lpx;
        float off0 = omb[((2*k)   << 14) + gxp];
        float off1 = omb[((2*k+1) << 14) + gxp];
        float mk   = omb[((18+k)  << 14) + gxp];   // sigmoided in K1

        float pyf = (float)y   + (float)(k/3) - 1.f + off0;
        float pxg = (float)gxp + (float)(k%3) - 1.f + off1;
        float fy = floorf(pyf), fx = floorf(pxg);
        int y0 = (int)fy, x0 = (int)fx;
        float wy = pyf - fy, wx = pxg - fx;
        float oy = 1.f - wy, ox = 1.f - wx;
        bool yv0 = (unsigned)y0     < (unsigned)HH;
        bool yv1 = (unsigned)(y0+1) < (unsigned)HH;
        bool xv0 = (unsigned)x0     < (unsigned)WW;
        bool xv1 = (unsigned)(x0+1) < (unsigned)WW;
        int y0c = min(max(y0, 0), 127);
        int x0c = min(max(x0, 0), 127);
        int dy = min(max(y0+1, 0), 127) - y0c;   // 0 or 1
        int dx = min(max(x0+1, 0), 127) - x0c;   // 0 or 1
        unsigned a = (unsigned)((y0c << 7) + x0c) | ((unsigned)dx << 14) | ((unsigned)dy << 15);
        float w00 = (yv0 && xv0) ? oy*ox*mk : 0.f;
        float w01 = (yv0 && xv1) ? oy*wx*mk : 0.f;
        float w10 = (yv1 && xv0) ? wy*ox*mk : 0.f;
        float w11 = (yv1 && xv1) ? wy*wx*mk : 0.f;
        pl_a[i]   = a;
        pl_w01[i] = pk2u(w00, w01);
        pl_w23[i] = pk2u(w10, w11);
    }
    __syncthreads();

    f32x4 acc0 = {0.f, 0.f, 0.f, 0.f};
    f32x4 acc1 = {0.f, 0.f, 0.f, 0.f};

    const unsigned* wbase = wmf + (wv*64 + lane)*72;

#pragma unroll
    for (int ch = 0; ch < 2; ++ch) {
        // A-fragments for this chunk: 9 x dwordx4 = 18 kb16 fragments, registers
        uint4 wreg[9];
#pragma unroll
        for (int q = 0; q < 9; ++q)
            wreg[q] = *(const uint4*)&wbase[ch*36 + q*4];

        // phase A: stage 144 pairs x 32 px samples (2 channels per item)
#pragma unroll 1
        for (int i = tid; i < 4608; i += 256) {
            int Pl  = i >> 5;
            int lpx = i & 31;
            int cp  = Pl / 9;
            int kt  = Pl - cp*9;
            unsigned a = pl_a[kt*32 + lpx];
            h2 hw01 = u2h(pl_w01[kt*32 + lpx]);
            h2 hw23 = u2h(pl_w23[kt*32 + lpx]);
            int i00 = (int)(a & 0x3FFFu);
            int dx  = (int)((a >> 14) & 1u);
            int dyo = (int)((a >> 15) & 1u) << 7;
            float w00 = (float)hw01.x, w01 = (float)hw01.y;
            float w10 = (float)hw23.x, w11 = (float)hw23.y;
            int i10 = i00 + dyo;
            const float* s0p = f1b + ((ch*32 + 2*cp) << 14);
            const float* s1p = s0p + (1 << 14);
            float sa = w00*s0p[i00] + w01*s0p[i00+dx] + w10*s0p[i10] + w11*s0p[i10+dx];
            float sb = w00*s1p[i00] + w01*s1p[i00+dx] + w10*s1p[i10] + w11*s1p[i10+dx];
            sl[lpx*146 + Pl] = pk2u(sa, sb);
        }
        __syncthreads();

        // phase B: 18 kb16 x 2 px-tiles MFMA
        const unsigned* b0p = &sl[(row     )*146 + ksel*2];
        const unsigned* b1p = &sl[(16+row  )*146 + ksel*2];
#pragma unroll
        for (int kbl = 0; kbl < 18; ++kbl) {
            U2H wa;
            uint4 wq = wreg[kbl >> 1];
            if (kbl & 1) { wa.u.x = wq.z; wa.u.y = wq.w; }
            else         { wa.u.x = wq.x; wa.u.y = wq.y; }
            U2H b0, b1;
            b0.u = *(const uint2*)&b0p[kbl*8];
            b1.u = *(const uint2*)&b1p[kbl*8];
            acc0 = __builtin_amdgcn_mfma_f32_16x16x16f16(wa.h, b0.h, acc0, 0, 0, 0);
            acc1 = __builtin_amdgcn_mfma_f32_16x16x16f16(wa.h, b1.h, acc1, 0, 0, 0);
        }
        __syncthreads();
    }

    // C/D: lane holds D[ksel*4 + rI][row] per px-tile
    int obase = ((b*CC) << 14) + (y << 7) + xq*32;
#pragma unroll
    for (int rI = 0; rI < 4; ++rI) {
        int och = wv*16 + ksel*4 + rI;
        aligned[obase + (och << 14) + row]      = acc0[rI];
        aligned[obase + (och << 14) + 16 + row] = acc1[rI];
    }
}

// ---------------- K3: per-channel partial sum / sumsq; grid 256 = (c, bimg)
__global__ __launch_bounds__(256) void k3_stats(
    const float* __restrict__ a, float* __restrict__ stats)
{
    int c = blockIdx.x & 63;
    int bimg = blockIdx.x >> 6;
    int tid = threadIdx.x;
    float s = 0.f, s2 = 0.f;
    const float* base = a + ((size_t)(bimg*CC + c) << 14);
    for (int i = tid*4; i < HWP; i += 256*4) {
        float4 v = *(const float4*)&base[i];
        s  += v.x + v.y + v.z + v.w;
        s2 += v.x*v.x + v.y*v.y + v.z*v.z + v.w*v.w;
    }
    for (int off = 32; off > 0; off >>= 1) {
        s  += __shfl_down(s,  off, 64);
        s2 += __shfl_down(s2, off, 64);
    }
    __shared__ float rs[4], rs2[4];
    int w = tid >> 6;
    if ((tid & 63) == 0) { rs[w] = s; rs2[w] = s2; }
    __syncthreads();
    if (tid == 0) {
        stats[bimg*128 + c]      = rs[0] + rs[1] + rs[2] + rs[3];
        stats[bimg*128 + 64 + c] = rs2[0] + rs2[1] + rs2[2] + rs2[3];
    }
}

// ---------------- K4: in-place normalize + affine (combines 4 partials)
__global__ __launch_bounds__(256) void k4_norm(
    float* __restrict__ a, const float* __restrict__ stats,
    const float* __restrict__ gamma, const float* __restrict__ beta)
{
    const float invN = 1.f / 65536.f;
    int n4 = (BB*CC*HWP) / 4;
    for (int i4 = blockIdx.x*256 + threadIdx.x; i4 < n4; i4 += gridDim.x*256) {
        int c = (i4 >> 12) & 63;
        float sm  = stats[c] + stats[128+c] + stats[256+c] + stats[384+c];
        float sq  = stats[64+c] + stats[192+c] + stats[320+c] + stats[448+c];
        float mean = sm * invN;
        float var  = sq * invN - mean*mean;
        float sc = gamma[c] * rsqrtf(var + 1e-5f);
        float sh = beta[c] - mean*sc;
        float4 v = ((const float4*)a)[i4];
        v.x = v.x*sc + sh; v.y = v.y*sc + sh;
        v.z = v.z*sc + sh; v.w = v.w*sc + sh;
        ((float4*)a)[i4] = v;
    }
}

extern "C" void kernel_launch(void* const* d_in, const int* in_sizes, int n_in,
                              void* d_out, int out_size, void* d_ws, size_t ws_size,
                              hipStream_t stream)
{
    const float* f1    = (const float*)d_in[0];
    const float* f3    = (const float*)d_in[1];
    const float* ow    = (const float*)d_in[2];
    const float* ob    = (const float*)d_in[3];
    const float* mw    = (const float*)d_in[4];
    const float* gamma = (const float*)d_in[5];
    const float* beta  = (const float*)d_in[6];
    float* out = (float*)d_out;

    float* om    = (float*)d_ws;                  // [4][27][128][128] = 7,077,888 B
    float* stats = om + 4*27*HWP;                 // [512] floats
    unsigned* owt2 = (unsigned*)(stats + 512);    // [3][64][96] u32 = 73,728 B
    unsigned* wmf  = owt2 + 3*64*96;              // [256][36][2] u32 = 73,728 B

    const int lds2 = (864 + 32*146) * 4;          // 22,144 B
    (void)hipFuncSetAttribute((const void*)k2_deform,
        hipFuncAttributeMaxDynamicSharedMemorySize, lds2);

    hipLaunchKernelGGL(k0_wt, dim3(133), dim3(256), 0, stream, ow, mw, owt2, wmf);
    hipLaunchKernelGGL(k1_offset_conv, dim3(256, 3), dim3(256), 0, stream,
                       f1, f3, owt2, ob, om);
    hipLaunchKernelGGL(k2_deform, dim3(2048), dim3(256), lds2, stream,
                       f1, wmf, om, out);
    hipLaunchKernelGGL(k3_stats, dim3(256), dim3(256), 0, stream, out, stats);
    hipLaunchKernelGGL(k4_norm, dim3(2048), dim3(256), 0, stream,
                       out, stats, gamma, beta);
}

// Round 10
// 189.303 us; speedup vs baseline: 4.6530x; 1.0044x over previous
//
#include <hip/hip_runtime.h>
#include <math.h>

#define BB 4
#define CC 64
#define HH 128
#define WW 128
#define HWP 16384

typedef _Float16 h2 __attribute__((ext_vector_type(2)));
typedef _Float16 h4 __attribute__((ext_vector_type(4)));
typedef __fp16  p2 __attribute__((ext_vector_type(2)));   // cvt_pkrtz's return type
typedef float f32x4 __attribute__((ext_vector_type(4)));
union HU { unsigned u; h2 h; p2 p; };
union U2H { uint2 u; h4 h; };
static __device__ __forceinline__ h2 u2h(unsigned x){ HU v; v.u = x; return v.h; }
static __device__ __forceinline__ unsigned pk2u(float a, float b){
    HU v; v.p = __builtin_amdgcn_cvt_pkrtz(a, b); return v.u;
}

// ---------------- K0: pack weights.
// owt2 [grp][cp][k*9+t] (u32 half2, stride 96): offset-conv weights (for K1).
// wmf: deform-conv weights as MFMA A-fragments for v_mfma_f32_16x16x16_f16.
//   u32 index ((r*64 + l)*36 + kb)*2 + j holds halves A[r*16 + (l&15)][kappa],
//   kappa = kb*16 + (l>>4)*4 + 2j + {0,1};  kappa -> pair P = kappa/2,
//   P = cp*9 + ktap, channels (2cp, 2cp+1) at tap ktap.
__global__ __launch_bounds__(256) void k0_wt(
    const float* __restrict__ ow, const float* __restrict__ mw,
    unsigned* __restrict__ owt2, unsigned* __restrict__ wmf)
{
    int i = blockIdx.x*256 + threadIdx.x;
    if (i < 15552) {                           // 3*64*81
        int cpl = i / 81;                      // grp*64 + cp
        int r   = i % 81;                      // k*9 + t
        int k = r / 9, t = r % 9;
        int grp = cpl >> 6, cp = cpl & 63;
        int o = grp*9 + k;
        int c0 = cp*2;
        float lo = ow[(o*128 + c0    )*9 + t];
        float hi = ow[(o*128 + c0 + 1)*9 + t];
        owt2[cpl*96 + r] = pk2u(lo, hi);
    } else if (i < 15552 + 18432) {            // wmf: 4*64*36*2
        int idx = i - 15552;
        int j   = idx & 1;
        int t   = idx >> 1;                    // 0..9215
        int kb  = t % 36;
        int rl  = t / 36;                      // 0..255
        int l   = rl & 63;
        int r   = rl >> 6;
        int row = l & 15, ksel = l >> 4;
        int och = r*16 + row;
        int P   = kb*8 + ksel*2 + j;           // pair index 0..287
        int cp  = P / 9;
        int kt  = P - cp*9;
        float lo = mw[och*576 + (2*cp    )*9 + kt];
        float hi = mw[och*576 + (2*cp + 1)*9 + kt];
        wmf[idx] = pk2u(lo, hi);
    }
}

// ---------------- K1: 3x3 conv over concat[f1,f3] -> om [B][27][H][W]
// f16-dot2 core: channel pairs packed to half2, weights via wave-uniform
// s_loads. Group 2 (channels 18..26) gets sigmoid applied (mask).
__global__ __launch_bounds__(256) void k1_offset_conv(
    const float* __restrict__ f1, const float* __restrict__ f3,
    const unsigned* __restrict__ owt2, const float* __restrict__ ob,
    float* __restrict__ om)
{
    int grp = blockIdx.y;          // 0..2
    int pix = blockIdx.x*256 + threadIdx.x;
    int b = pix >> 14;
    int y = (pix >> 7) & 127;
    int x = pix & 127;

    int   toff[9];
    float tval[9];
#pragma unroll
    for (int t = 0; t < 9; ++t) {
        int yy = y + t/3 - 1;
        int xx = x + (t % 3) - 1;
        bool ok = ((unsigned)yy < (unsigned)HH) && ((unsigned)xx < (unsigned)WW);
        tval[t] = ok ? 1.f : 0.f;
        toff[t] = ok ? (yy*WW + xx) : 0;
    }

    float acc[9];
#pragma unroll
    for (int k = 0; k < 9; ++k) acc[k] = ob[grp*9 + k];

    const float* base0 = f1 + ((size_t)(b*CC) << 14);
    const float* base1 = f3 + ((size_t)(b*CC) << 14);
    const unsigned* wgs = owt2 + grp*64*96;    // uniform base

    for (int half = 0; half < 2; ++half) {
        const float* srcb = (half == 0) ? base0 : base1;
        for (int cph = 0; cph < 32; ++cph) {
            const float* srcA = srcb + ((cph*2) << 14);
            const float* srcB = srcA + (1 << 14);
            h2 v[9];
#pragma unroll
            for (int t = 0; t < 9; ++t) {
                float va = tval[t] * srcA[toff[t]];
                float vb = tval[t] * srcB[toff[t]];
                v[t] = u2h(pk2u(va, vb));
            }
            const unsigned* wr = wgs + (half*32 + cph)*96;   // uniform
#pragma unroll
            for (int k = 0; k < 9; ++k)
#pragma unroll
                for (int t = 0; t < 9; ++t)
                    acc[k] = __builtin_amdgcn_fdot2(u2h(wr[k*9 + t]), v[t], acc[k], false);
        }
    }

    int obase = ((b*27 + grp*9) << 14) + (y << 7) + x;
#pragma unroll
    for (int k = 0; k < 9; ++k) {
        float a = acc[k];
        if (grp == 2) a = 1.f / (1.f + __expf(-a));   // sigmoid for mask group
        om[obase + (k << 14)] = a;
    }
}

// ---------------- K2: deformable conv, MFMA phase B.
// block = quarter-row (32 px), 4 waves; grid 2048.
// Wave wv owns out-tile [wv*16, wv*16+16) x both 16-px tiles.
// K = 576 as 2 chunks of 288. Phase A unrolled x3 for load-level parallelism.
// LDS: pl_a 288 + pl_w 576 (uint2) + sl[32][146] = 22,144 B.
__global__ __launch_bounds__(256) void k2_deform(
    const float* __restrict__ f1, const unsigned* __restrict__ wmf,
    const float* __restrict__ om, float* __restrict__ aligned)
{
    extern __shared__ unsigned lds[];
    unsigned* pl_a = lds;            // [9][32] addr|dx<<14|dy<<15
    unsigned* pl_w = lds + 288;      // [9][32] x uint2 {half2(w00,w01), half2(w10,w11)}
    unsigned* sl   = lds + 864;      // [32][146] half2 samples

    int blk = blockIdx.x;        // b(2) y(7) xq(2)
    int xq = blk & 3;
    int y  = (blk >> 2) & 127;
    int b  = blk >> 9;

    int tid  = threadIdx.x;
    int lane = tid & 63;
    int wv   = tid >> 6;         // wave id = out-tile index r
    int row  = lane & 15;
    int ksel = lane >> 4;

    const float* omb = om + ((b*27) << 14) + (y << 7);
    const float* f1b = f1 + ((size_t)(b*CC) << 14);

    // ---- param pre-phase: 288 items (k, px)
    for (int i = tid; i < 288; i += 256) {
        int k = i >> 5, lpx = i & 31;
        int gxp = xq*32 + lpx;
        float off0 = omb[((2*k)   << 14) + gxp];
        float off1 = omb[((2*k+1) << 14) + gxp];
        float mk   = omb[((18+k)  << 14) + gxp];   // sigmoided in K1

        float pyf = (float)y   + (float)(k/3) - 1.f + off0;
        float pxg = (float)gxp + (float)(k%3) - 1.f + off1;
        float fy = floorf(pyf), fx = floorf(pxg);
        int y0 = (int)fy, x0 = (int)fx;
        float wy = pyf - fy, wx = pxg - fx;
        float oy = 1.f - wy, ox = 1.f - wx;
        bool yv0 = (unsigned)y0     < (unsigned)HH;
        bool yv1 = (unsigned)(y0+1) < (unsigned)HH;
        bool xv0 = (unsigned)x0     < (unsigned)WW;
        bool xv1 = (unsigned)(x0+1) < (unsigned)WW;
        int y0c = min(max(y0, 0), 127);
        int x0c = min(max(x0, 0), 127);
        int dy = min(max(y0+1, 0), 127) - y0c;   // 0 or 1
        int dx = min(max(x0+1, 0), 127) - x0c;   // 0 or 1
        unsigned a = (unsigned)((y0c << 7) + x0c) | ((unsigned)dx << 14) | ((unsigned)dy << 15);
        float w00 = (yv0 && xv0) ? oy*ox*mk : 0.f;
        float w01 = (yv0 && xv1) ? oy*wx*mk : 0.f;
        float w10 = (yv1 && xv0) ? wy*ox*mk : 0.f;
        float w11 = (yv1 && xv1) ? wy*wx*mk : 0.f;
        pl_a[i] = a;
        pl_w[i*2]     = pk2u(w00, w01);
        pl_w[i*2 + 1] = pk2u(w10, w11);
    }
    __syncthreads();

    f32x4 acc0 = {0.f, 0.f, 0.f, 0.f};
    f32x4 acc1 = {0.f, 0.f, 0.f, 0.f};

    const unsigned* wbase = wmf + (wv*64 + lane)*72;

#pragma unroll 1
    for (int ch = 0; ch < 2; ++ch) {
        // A-fragments for this chunk: 9 x dwordx4 = 18 kb16 fragments, registers
        uint4 wreg[9];
#pragma unroll
        for (int q = 0; q < 9; ++q)
            wreg[q] = *(const uint4*)&wbase[ch*36 + q*4];

        // phase A: 4608 items = 18/thread; unroll 3 -> ~24 loads in flight/lane
#pragma unroll 3
        for (int it = 0; it < 18; ++it) {
            int i   = it*256 + tid;
            int Pl  = i >> 5;
            int lpx = i & 31;
            int cp  = Pl / 9;
            int kt  = Pl - cp*9;
            int pidx = kt*32 + lpx;
            unsigned a = pl_a[pidx];
            uint2 wpk = *(const uint2*)&pl_w[pidx*2];
            h2 hw01 = u2h(wpk.x);
            h2 hw23 = u2h(wpk.y);
            int i00 = (int)(a & 0x3FFFu);
            int dx  = (int)((a >> 14) & 1u);
            int dyo = (int)((a >> 15) & 1u) << 7;
            float w00 = (float)hw01.x, w01 = (float)hw01.y;
            float w10 = (float)hw23.x, w11 = (float)hw23.y;
            int i10 = i00 + dyo;
            const float* s0p = f1b + ((ch*32 + 2*cp) << 14);
            const float* s1p = s0p + (1 << 14);
            float sa = w00*s0p[i00] + w01*s0p[i00+dx] + w10*s0p[i10] + w11*s0p[i10+dx];
            float sb = w00*s1p[i00] + w01*s1p[i00+dx] + w10*s1p[i10] + w11*s1p[i10+dx];
            sl[lpx*146 + Pl] = pk2u(sa, sb);
        }
        __syncthreads();

        // phase B: 18 kb16 x 2 px-tiles MFMA
        const unsigned* b0p = &sl[(row     )*146 + ksel*2];
        const unsigned* b1p = &sl[(16+row  )*146 + ksel*2];
#pragma unroll
        for (int kbl = 0; kbl < 18; ++kbl) {
            U2H wa;
            uint4 wq = wreg[kbl >> 1];
            if (kbl & 1) { wa.u.x = wq.z; wa.u.y = wq.w; }
            else         { wa.u.x = wq.x; wa.u.y = wq.y; }
            U2H b0, b1;
            b0.u = *(const uint2*)&b0p[kbl*8];
            b1.u = *(const uint2*)&b1p[kbl*8];
            acc0 = __builtin_amdgcn_mfma_f32_16x16x16f16(wa.h, b0.h, acc0, 0, 0, 0);
            acc1 = __builtin_amdgcn_mfma_f32_16x16x16f16(wa.h, b1.h, acc1, 0, 0, 0);
        }
        __syncthreads();
    }

    // C/D: lane holds D[ksel*4 + rI][row] per px-tile
    int obase = ((b*CC) << 14) + (y << 7) + xq*32;
#pragma unroll
    for (int rI = 0; rI < 4; ++rI) {
        int och = wv*16 + ksel*4 + rI;
        aligned[obase + (och << 14) + row]      = acc0[rI];
        aligned[obase + (och << 14) + 16 + row] = acc1[rI];
    }
}

// ---------------- K3: per-channel partial sum / sumsq; grid 256 = (c, bimg)
__global__ __launch_bounds__(256) void k3_stats(
    const float* __restrict__ a, float* __restrict__ stats)
{
    int c = blockIdx.x & 63;
    int bimg = blockIdx.x >> 6;
    int tid = threadIdx.x;
    float s = 0.f, s2 = 0.f;
    const float* base = a + ((size_t)(bimg*CC + c) << 14);
    for (int i = tid*4; i < HWP; i += 256*4) {
        float4 v = *(const float4*)&base[i];
        s  += v.x + v.y + v.z + v.w;
        s2 += v.x*v.x + v.y*v.y + v.z*v.z + v.w*v.w;
    }
    for (int off = 32; off > 0; off >>= 1) {
        s  += __shfl_down(s,  off, 64);
        s2 += __shfl_down(s2, off, 64);
    }
    __shared__ float rs[4], rs2[4];
    int w = tid >> 6;
    if ((tid & 63) == 0) { rs[w] = s; rs2[w] = s2; }
    __syncthreads();
    if (tid == 0) {
        stats[bimg*128 + c]      = rs[0] + rs[1] + rs[2] + rs[3];
        stats[bimg*128 + 64 + c] = rs2[0] + rs2[1] + rs2[2] + rs2[3];
    }
}

// ---------------- K4: in-place normalize + affine (combines 4 partials)
__global__ __launch_bounds__(256) void k4_norm(
    float* __restrict__ a, const float* __restrict__ stats,
    const float* __restrict__ gamma, const float* __restrict__ beta)
{
    const float invN = 1.f / 65536.f;
    int n4 = (BB*CC*HWP) / 4;
    for (int i4 = blockIdx.x*256 + threadIdx.x; i4 < n4; i4 += gridDim.x*256) {
        int c = (i4 >> 12) & 63;
        float sm  = stats[c] + stats[128+c] + stats[256+c] + stats[384+c];
        float sq  = stats[64+c] + stats[192+c] + stats[320+c] + stats[448+c];
        float mean = sm * invN;
        float var  = sq * invN - mean*mean;
        float sc = gamma[c] * rsqrtf(var + 1e-5f);
        float sh = beta[c] - mean*sc;
        float4 v = ((const float4*)a)[i4];
        v.x = v.x*sc + sh; v.y = v.y*sc + sh;
        v.z = v.z*sc + sh; v.w = v.w*sc + sh;
        ((float4*)a)[i4] = v;
    }
}

extern "C" void kernel_launch(void* const* d_in, const int* in_sizes, int n_in,
                              void* d_out, int out_size, void* d_ws, size_t ws_size,
                              hipStream_t stream)
{
    const float* f1    = (const float*)d_in[0];
    const float* f3    = (const float*)d_in[1];
    const float* ow    = (const float*)d_in[2];
    const float* ob    = (const float*)d_in[3];
    const float* mw    = (const float*)d_in[4];
    const float* gamma = (const float*)d_in[5];
    const float* beta  = (const float*)d_in[6];
    float* out = (float*)d_out;

    float* om    = (float*)d_ws;                  // [4][27][128][128] = 7,077,888 B
    float* stats = om + 4*27*HWP;                 // [512] floats
    unsigned* owt2 = (unsigned*)(stats + 512);    // [3][64][96] u32 = 73,728 B
    unsigned* wmf  = owt2 + 3*64*96;              // [256][36][2] u32 = 73,728 B

    const int lds2 = (864 + 32*146) * 4;          // 22,144 B
    (void)hipFuncSetAttribute((const void*)k2_deform,
        hipFuncAttributeMaxDynamicSharedMemorySize, lds2);

    hipLaunchKernelGGL(k0_wt, dim3(133), dim3(256), 0, stream, ow, mw, owt2, wmf);
    hipLaunchKernelGGL(k1_offset_conv, dim3(256, 3), dim3(256), 0, stream,
                       f1, f3, owt2, ob, om);
    hipLaunchKernelGGL(k2_deform, dim3(2048), dim3(256), lds2, stream,
                       f1, wmf, om, out);
    hipLaunchKernelGGL(k3_stats, dim3(256), dim3(256), 0, stream, out, stats);
    hipLaunchKernelGGL(k4_norm, dim3(2048), dim3(256), 0, stream,
                       out, stats, gamma, beta);
}

// Round 11
// 187.984 us; speedup vs baseline: 4.6856x; 1.0070x over previous
//
#include <hip/hip_runtime.h>
#include <math.h>

#define BB 4
#define CC 64
#define HH 128
#define WW 128
#define HWP 16384

typedef _Float16 h2 __attribute__((ext_vector_type(2)));
typedef _Float16 h4 __attribute__((ext_vector_type(4)));
typedef __fp16  p2 __attribute__((ext_vector_type(2)));   // cvt_pkrtz's return type
typedef float f32x4 __attribute__((ext_vector_type(4)));
union HU { unsigned u; h2 h; p2 p; };
union U2H { uint2 u; h4 h; };
static __device__ __forceinline__ h2 u2h(unsigned x){ HU v; v.u = x; return v.h; }
static __device__ __forceinline__ unsigned pk2u(float a, float b){
    HU v; v.p = __builtin_amdgcn_cvt_pkrtz(a, b); return v.u;
}

// ---------------- K0: pack weights.
// owt2 [grp][cp][k*9+t] (u32 half2, stride 96): offset-conv weights (for K1).
// wmf: deform-conv weights as MFMA A-fragments for v_mfma_f32_16x16x16_f16.
//   u32 index ((r*64 + l)*36 + kb)*2 + j holds halves A[r*16 + (l&15)][kappa],
//   kappa = kb*16 + (l>>4)*4 + 2j + {0,1};  kappa -> pair P = kappa/2,
//   P = cp*9 + ktap, channels (2cp, 2cp+1) at tap ktap.
__global__ __launch_bounds__(256) void k0_wt(
    const float* __restrict__ ow, const float* __restrict__ mw,
    unsigned* __restrict__ owt2, unsigned* __restrict__ wmf)
{
    int i = blockIdx.x*256 + threadIdx.x;
    if (i < 15552) {                           // 3*64*81
        int cpl = i / 81;                      // grp*64 + cp
        int r   = i % 81;                      // k*9 + t
        int k = r / 9, t = r % 9;
        int grp = cpl >> 6, cp = cpl & 63;
        int o = grp*9 + k;
        int c0 = cp*2;
        float lo = ow[(o*128 + c0    )*9 + t];
        float hi = ow[(o*128 + c0 + 1)*9 + t];
        owt2[cpl*96 + r] = pk2u(lo, hi);
    } else if (i < 15552 + 18432) {            // wmf: 4*64*36*2
        int idx = i - 15552;
        int j   = idx & 1;
        int t   = idx >> 1;                    // 0..9215
        int kb  = t % 36;
        int rl  = t / 36;                      // 0..255
        int l   = rl & 63;
        int r   = rl >> 6;
        int row = l & 15, ksel = l >> 4;
        int och = r*16 + row;
        int P   = kb*8 + ksel*2 + j;           // pair index 0..287
        int cp  = P / 9;
        int kt  = P - cp*9;
        float lo = mw[och*576 + (2*cp    )*9 + kt];
        float hi = mw[och*576 + (2*cp + 1)*9 + kt];
        wmf[idx] = pk2u(lo, hi);
    }
}

// ---------------- K1: 3x3 conv over concat[f1,f3] -> om [B][27][H][W]
// f16-dot2 core: channel pairs packed to half2, weights via wave-uniform
// s_loads. Group 2 (channels 18..26) gets sigmoid applied (mask).
__global__ __launch_bounds__(256) void k1_offset_conv(
    const float* __restrict__ f1, const float* __restrict__ f3,
    const unsigned* __restrict__ owt2, const float* __restrict__ ob,
    float* __restrict__ om)
{
    int grp = blockIdx.y;          // 0..2
    int pix = blockIdx.x*256 + threadIdx.x;
    int b = pix >> 14;
    int y = (pix >> 7) & 127;
    int x = pix & 127;

    int   toff[9];
    float tval[9];
#pragma unroll
    for (int t = 0; t < 9; ++t) {
        int yy = y + t/3 - 1;
        int xx = x + (t % 3) - 1;
        bool ok = ((unsigned)yy < (unsigned)HH) && ((unsigned)xx < (unsigned)WW);
        tval[t] = ok ? 1.f : 0.f;
        toff[t] = ok ? (yy*WW + xx) : 0;
    }

    float acc[9];
#pragma unroll
    for (int k = 0; k < 9; ++k) acc[k] = ob[grp*9 + k];

    const float* base0 = f1 + ((size_t)(b*CC) << 14);
    const float* base1 = f3 + ((size_t)(b*CC) << 14);
    const unsigned* wgs = owt2 + grp*64*96;    // uniform base

    for (int half = 0; half < 2; ++half) {
        const float* srcb = (half == 0) ? base0 : base1;
        for (int cph = 0; cph < 32; ++cph) {
            const float* srcA = srcb + ((cph*2) << 14);
            const float* srcB = srcA + (1 << 14);
            h2 v[9];
#pragma unroll
            for (int t = 0; t < 9; ++t) {
                float va = tval[t] * srcA[toff[t]];
                float vb = tval[t] * srcB[toff[t]];
                v[t] = u2h(pk2u(va, vb));
            }
            const unsigned* wr = wgs + (half*32 + cph)*96;   // uniform
#pragma unroll
            for (int k = 0; k < 9; ++k)
#pragma unroll
                for (int t = 0; t < 9; ++t)
                    acc[k] = __builtin_amdgcn_fdot2(u2h(wr[k*9 + t]), v[t], acc[k], false);
        }
    }

    int obase = ((b*27 + grp*9) << 14) + (y << 7) + x;
#pragma unroll
    for (int k = 0; k < 9; ++k) {
        float a = acc[k];
        if (grp == 2) a = 1.f / (1.f + __expf(-a));   // sigmoid for mask group
        om[obase + (k << 14)] = a;
    }
}

// ---------------- K2: deformable conv, MFMA phase B, SINGLE-PASS LDS.
// block = quarter-row (32 px), 4 waves; grid 2048 = 8 blocks/CU.
// LDS must be < 20 KB for 8 blocks/CU (R9/R10 at 22.1KB ran 7+1 two-pass).
// K = 576 as 2 chunks x 2 halves of 72 pairs; sl[32][74] per half.
// LDS: params 864 + sl 2368 = 3232 u32 = 12,928 B -> 12 blocks/CU cap.
__global__ __launch_bounds__(256) void k2_deform(
    const float* __restrict__ f1, const unsigned* __restrict__ wmf,
    const float* __restrict__ om, float* __restrict__ aligned)
{
    extern __shared__ unsigned lds[];
    unsigned* pl_a = lds;            // [9][32] addr|dx<<14|dy<<15
    unsigned* pl_w = lds + 288;      // [9][32] x uint2 {half2(w00,w01), half2(w10,w11)}
    unsigned* sl   = lds + 864;      // [32][74] half2 samples (one 72-pair half)

    int blk = blockIdx.x;        // b(2) y(7) xq(2)
    int xq = blk & 3;
    int y  = (blk >> 2) & 127;
    int b  = blk >> 9;

    int tid  = threadIdx.x;
    int lane = tid & 63;
    int wv   = tid >> 6;         // wave id = out-tile index r
    int row  = lane & 15;
    int ksel = lane >> 4;

    const float* omb = om + ((b*27) << 14) + (y << 7);
    const float* f1b = f1 + ((size_t)(b*CC) << 14);

    // ---- param pre-phase: 288 items (k, px)
    for (int i = tid; i < 288; i += 256) {
        int k = i >> 5, lpx = i & 31;
        int gxp = xq*32 + lpx;
        float off0 = omb[((2*k)   << 14) + gxp];
        float off1 = omb[((2*k+1) << 14) + gxp];
        float mk   = omb[((18+k)  << 14) + gxp];   // sigmoided in K1

        float pyf = (float)y   + (float)(k/3) - 1.f + off0;
        float pxg = (float)gxp + (float)(k%3) - 1.f + off1;
        float fy = floorf(pyf), fx = floorf(pxg);
        int y0 = (int)fy, x0 = (int)fx;
        float wy = pyf - fy, wx = pxg - fx;
        float oy = 1.f - wy, ox = 1.f - wx;
        bool yv0 = (unsigned)y0     < (unsigned)HH;
        bool yv1 = (unsigned)(y0+1) < (unsigned)HH;
        bool xv0 = (unsigned)x0     < (unsigned)WW;
        bool xv1 = (unsigned)(x0+1) < (unsigned)WW;
        int y0c = min(max(y0, 0), 127);
        int x0c = min(max(x0, 0), 127);
        int dy = min(max(y0+1, 0), 127) - y0c;   // 0 or 1
        int dx = min(max(x0+1, 0), 127) - x0c;   // 0 or 1
        unsigned a = (unsigned)((y0c << 7) + x0c) | ((unsigned)dx << 14) | ((unsigned)dy << 15);
        float w00 = (yv0 && xv0) ? oy*ox*mk : 0.f;
        float w01 = (yv0 && xv1) ? oy*wx*mk : 0.f;
        float w10 = (yv1 && xv0) ? wy*ox*mk : 0.f;
        float w11 = (yv1 && xv1) ? wy*wx*mk : 0.f;
        pl_a[i] = a;
        pl_w[i*2]     = pk2u(w00, w01);
        pl_w[i*2 + 1] = pk2u(w10, w11);
    }
    __syncthreads();

    f32x4 acc0 = {0.f, 0.f, 0.f, 0.f};
    f32x4 acc1 = {0.f, 0.f, 0.f, 0.f};

    const unsigned* wbase = wmf + (wv*64 + lane)*72;

#pragma unroll 1
    for (int ch = 0; ch < 2; ++ch) {
        // A-fragments for this chunk: 9 x dwordx4 = 18 kb16 fragments, registers
        uint4 wreg[9];
#pragma unroll
        for (int q = 0; q < 9; ++q)
            wreg[q] = *(const uint4*)&wbase[ch*36 + q*4];

#pragma unroll
        for (int hf = 0; hf < 2; ++hf) {
            // phase A: 72 pairs x 32 px = 2304 items = 9/thread
#pragma unroll 3
            for (int it = 0; it < 9; ++it) {
                int i    = it*256 + tid;
                int Phc  = hf*72 + (i >> 5);      // pair within chunk 0..143
                int lpx  = i & 31;
                int cp   = Phc / 9;               // 0..15 within chunk
                int kt   = Phc - cp*9;
                int pidx = kt*32 + lpx;
                unsigned a = pl_a[pidx];
                uint2 wpk = *(const uint2*)&pl_w[pidx*2];
                h2 hw01 = u2h(wpk.x);
                h2 hw23 = u2h(wpk.y);
                int i00 = (int)(a & 0x3FFFu);
                int dx  = (int)((a >> 14) & 1u);
                int dyo = (int)((a >> 15) & 1u) << 7;
                float w00 = (float)hw01.x, w01 = (float)hw01.y;
                float w10 = (float)hw23.x, w11 = (float)hw23.y;
                int i10 = i00 + dyo;
                const float* s0p = f1b + ((ch*32 + 2*cp) << 14);
                const float* s1p = s0p + (1 << 14);
                float sa = w00*s0p[i00] + w01*s0p[i00+dx] + w10*s0p[i10] + w11*s0p[i10+dx];
                float sb = w00*s1p[i00] + w01*s1p[i00+dx] + w10*s1p[i10] + w11*s1p[i10+dx];
                sl[lpx*74 + (Phc - hf*72)] = pk2u(sa, sb);
            }
            __syncthreads();

            // phase B: 9 kb16 x 2 px-tiles MFMA (kbl global in [hf*9, hf*9+9))
            const unsigned* b0p = &sl[(row     )*74 + ksel*2];
            const unsigned* b1p = &sl[(16+row  )*74 + ksel*2];
#pragma unroll
            for (int kl = 0; kl < 9; ++kl) {
                int kbl = hf*9 + kl;
                U2H wa;
                uint4 wq = wreg[kbl >> 1];
                if (kbl & 1) { wa.u.x = wq.z; wa.u.y = wq.w; }
                else         { wa.u.x = wq.x; wa.u.y = wq.y; }
                U2H b0, b1;
                b0.u = *(const uint2*)&b0p[kl*8];
                b1.u = *(const uint2*)&b1p[kl*8];
                acc0 = __builtin_amdgcn_mfma_f32_16x16x16f16(wa.h, b0.h, acc0, 0, 0, 0);
                acc1 = __builtin_amdgcn_mfma_f32_16x16x16f16(wa.h, b1.h, acc1, 0, 0, 0);
            }
            __syncthreads();
        }
    }

    // C/D: lane holds D[ksel*4 + rI][row] per px-tile
    int obase = ((b*CC) << 14) + (y << 7) + xq*32;
#pragma unroll
    for (int rI = 0; rI < 4; ++rI) {
        int och = wv*16 + ksel*4 + rI;
        aligned[obase + (och << 14) + row]      = acc0[rI];
        aligned[obase + (och << 14) + 16 + row] = acc1[rI];
    }
}

// ---------------- K3: per-channel partial sum / sumsq; grid 256 = (c, bimg)
__global__ __launch_bounds__(256) void k3_stats(
    const float* __restrict__ a, float* __restrict__ stats)
{
    int c = blockIdx.x & 63;
    int bimg = blockIdx.x >> 6;
    int tid = threadIdx.x;
    float s = 0.f, s2 = 0.f;
    const float* base = a + ((size_t)(bimg*CC + c) << 14);
    for (int i = tid*4; i < HWP; i += 256*4) {
        float4 v = *(const float4*)&base[i];
        s  += v.x + v.y + v.z + v.w;
        s2 += v.x*v.x + v.y*v.y + v.z*v.z + v.w*v.w;
    }
    for (int off = 32; off > 0; off >>= 1) {
        s  += __shfl_down(s,  off, 64);
        s2 += __shfl_down(s2, off, 64);
    }
    __shared__ float rs[4], rs2[4];
    int w = tid >> 6;
    if ((tid & 63) == 0) { rs[w] = s; rs2[w] = s2; }
    __syncthreads();
    if (tid == 0) {
        stats[bimg*128 + c]      = rs[0] + rs[1] + rs[2] + rs[3];
        stats[bimg*128 + 64 + c] = rs2[0] + rs2[1] + rs2[2] + rs2[3];
    }
}

// ---------------- K4: in-place normalize + affine (combines 4 partials)
__global__ __launch_bounds__(256) void k4_norm(
    float* __restrict__ a, const float* __restrict__ stats,
    const float* __restrict__ gamma, const float* __restrict__ beta)
{
    const float invN = 1.f / 65536.f;
    int n4 = (BB*CC*HWP) / 4;
    for (int i4 = blockIdx.x*256 + threadIdx.x; i4 < n4; i4 += gridDim.x*256) {
        int c = (i4 >> 12) & 63;
        float sm  = stats[c] + stats[128+c] + stats[256+c] + stats[384+c];
        float sq  = stats[64+c] + stats[192+c] + stats[320+c] + stats[448+c];
        float mean = sm * invN;
        float var  = sq * invN - mean*mean;
        float sc = gamma[c] * rsqrtf(var + 1e-5f);
        float sh = beta[c] - mean*sc;
        float4 v = ((const float4*)a)[i4];
        v.x = v.x*sc + sh; v.y = v.y*sc + sh;
        v.z = v.z*sc + sh; v.w = v.w*sc + sh;
        ((float4*)a)[i4] = v;
    }
}

extern "C" void kernel_launch(void* const* d_in, const int* in_sizes, int n_in,
                              void* d_out, int out_size, void* d_ws, size_t ws_size,
                              hipStream_t stream)
{
    const float* f1    = (const float*)d_in[0];
    const float* f3    = (const float*)d_in[1];
    const float* ow    = (const float*)d_in[2];
    const float* ob    = (const float*)d_in[3];
    const float* mw    = (const float*)d_in[4];
    const float* gamma = (const float*)d_in[5];
    const float* beta  = (const float*)d_in[6];
    float* out = (float*)d_out;

    float* om    = (float*)d_ws;                  // [4][27][128][128] = 7,077,888 B
    float* stats = om + 4*27*HWP;                 // [512] floats
    unsigned* owt2 = (unsigned*)(stats + 512);    // [3][64][96] u32 = 73,728 B
    unsigned* wmf  = owt2 + 3*64*96;              // [256][36][2] u32 = 73,728 B

    const int lds2 = (864 + 32*74) * 4;           // 12,928 B -> 12 blocks/CU
    (void)hipFuncSetAttribute((const void*)k2_deform,
        hipFuncAttributeMaxDynamicSharedMemorySize, lds2);

    hipLaunchKernelGGL(k0_wt, dim3(133), dim3(256), 0, stream, ow, mw, owt2, wmf);
    hipLaunchKernelGGL(k1_offset_conv, dim3(256, 3), dim3(256), 0, stream,
                       f1, f3, owt2, ob, om);
    hipLaunchKernelGGL(k2_deform, dim3(2048), dim3(256), lds2, stream,
                       f1, wmf, om, out);
    hipLaunchKernelGGL(k3_stats, dim3(256), dim3(256), 0, stream, out, stats);
    hipLaunchKernelGGL(k4_norm, dim3(2048), dim3(256), 0, stream,
                       out, stats, gamma, beta);
}

// Round 12
// 129.632 us; speedup vs baseline: 6.7948x; 1.4501x over previous
//
#include <hip/hip_runtime.h>
#include <math.h>

#define BB 4
#define CC 64
#define HH 128
#define WW 128
#define HWP 16384

typedef _Float16 h2 __attribute__((ext_vector_type(2)));
typedef _Float16 h4 __attribute__((ext_vector_type(4)));
typedef __fp16  p2 __attribute__((ext_vector_type(2)));   // cvt_pkrtz's return type
typedef float f32x4 __attribute__((ext_vector_type(4)));
union HU { unsigned u; h2 h; p2 p; };
union U2H { uint2 u; h4 h; };
static __device__ __forceinline__ h2 u2h(unsigned x){ HU v; v.u = x; return v.h; }
static __device__ __forceinline__ unsigned pk2u(float a, float b){
    HU v; v.p = __builtin_amdgcn_cvt_pkrtz(a, b); return v.u;
}

// ---------------- kT: transpose f1 [C][H][W] -> f1t [H][W][C] (per batch)
__global__ __launch_bounds__(256) void kT(
    const float* __restrict__ f1, float* __restrict__ f1t)
{
    __shared__ float lt[64*129];
    int b = blockIdx.x >> 7, y = blockIdx.x & 127;
    int t = threadIdx.x;
    const float* src = f1 + (((size_t)b*64) << 14) + (y << 7);
#pragma unroll 4
    for (int i = 0; i < 32; ++i) {
        int idx = i*256 + t; int c = idx >> 7, x = idx & 127;
        lt[c*129 + x] = src[(c << 14) + x];
    }
    __syncthreads();
    float* dst = f1t + ((size_t)((b << 14) + (y << 7)))*64;
#pragma unroll 4
    for (int i = 0; i < 32; ++i) {
        int idx = i*256 + t; int x = idx >> 6, c = idx & 63;
        dst[x*64 + c] = lt[c*129 + x];
    }
}

// ---------------- K0: pack weights.
// owt2 [grp][cp][k*9+t] (u32 half2, stride 96): offset-conv weights (for K1).
// wmf: deform MFMA A-fragments, kappa order P = kt*32 + cp (tap-major):
//   u32 idx ((r*64+l)*36 + kb)*2 + j: P = kb*8 + (l>>4)*2 + j, kt = P>>5,
//   cp = P&31; halves = channels (2cp, 2cp+1) of out-ch r*16 + (l&15).
__global__ __launch_bounds__(256) void k0_wt(
    const float* __restrict__ ow, const float* __restrict__ mw,
    unsigned* __restrict__ owt2, unsigned* __restrict__ wmf)
{
    int i = blockIdx.x*256 + threadIdx.x;
    if (i < 15552) {                           // 3*64*81
        int cpl = i / 81;                      // grp*64 + cp
        int r   = i % 81;                      // k*9 + t
        int k = r / 9, t = r % 9;
        int grp = cpl >> 6, cp = cpl & 63;
        int o = grp*9 + k;
        int c0 = cp*2;
        float lo = ow[(o*128 + c0    )*9 + t];
        float hi = ow[(o*128 + c0 + 1)*9 + t];
        owt2[cpl*96 + r] = pk2u(lo, hi);
    } else if (i < 15552 + 18432) {            // wmf: 4*64*36*2
        int idx = i - 15552;
        int j   = idx & 1;
        int t2  = idx >> 1;                    // 0..9215
        int kb  = t2 % 36;
        int rl  = t2 / 36;                     // 0..255
        int l   = rl & 63;
        int r   = rl >> 6;
        int row = l & 15, ksel = l >> 4;
        int och = r*16 + row;
        int P   = kb*8 + ksel*2 + j;           // 0..287
        int kt  = P >> 5;                      // tap
        int cp  = P & 31;                      // channel pair
        float lo = mw[och*576 + (2*cp    )*9 + kt];
        float hi = mw[och*576 + (2*cp + 1)*9 + kt];
        wmf[idx] = pk2u(lo, hi);
    }
}

// ---------------- K1: 3x3 conv over concat[f1,f3] -> om [B][27][H][W]
// f16-dot2 core: channel pairs packed to half2, weights via wave-uniform
// s_loads. Group 2 (channels 18..26) gets sigmoid applied (mask).
__global__ __launch_bounds__(256) void k1_offset_conv(
    const float* __restrict__ f1, const float* __restrict__ f3,
    const unsigned* __restrict__ owt2, const float* __restrict__ ob,
    float* __restrict__ om)
{
    int grp = blockIdx.y;          // 0..2
    int pix = blockIdx.x*256 + threadIdx.x;
    int b = pix >> 14;
    int y = (pix >> 7) & 127;
    int x = pix & 127;

    int   toff[9];
    float tval[9];
#pragma unroll
    for (int t = 0; t < 9; ++t) {
        int yy = y + t/3 - 1;
        int xx = x + (t % 3) - 1;
        bool ok = ((unsigned)yy < (unsigned)HH) && ((unsigned)xx < (unsigned)WW);
        tval[t] = ok ? 1.f : 0.f;
        toff[t] = ok ? (yy*WW + xx) : 0;
    }

    float acc[9];
#pragma unroll
    for (int k = 0; k < 9; ++k) acc[k] = ob[grp*9 + k];

    const float* base0 = f1 + ((size_t)(b*CC) << 14);
    const float* base1 = f3 + ((size_t)(b*CC) << 14);
    const unsigned* wgs = owt2 + grp*64*96;    // uniform base

    for (int half = 0; half < 2; ++half) {
        const float* srcb = (half == 0) ? base0 : base1;
        for (int cph = 0; cph < 32; ++cph) {
            const float* srcA = srcb + ((cph*2) << 14);
            const float* srcB = srcA + (1 << 14);
            h2 v[9];
#pragma unroll
            for (int t = 0; t < 9; ++t) {
                float va = tval[t] * srcA[toff[t]];
                float vb = tval[t] * srcB[toff[t]];
                v[t] = u2h(pk2u(va, vb));
            }
            const unsigned* wr = wgs + (half*32 + cph)*96;   // uniform
#pragma unroll
            for (int k = 0; k < 9; ++k)
#pragma unroll
                for (int t = 0; t < 9; ++t)
                    acc[k] = __builtin_amdgcn_fdot2(u2h(wr[k*9 + t]), v[t], acc[k], false);
        }
    }

    int obase = ((b*27 + grp*9) << 14) + (y << 7) + x;
#pragma unroll
    for (int k = 0; k < 9; ++k) {
        float a = acc[k];
        if (grp == 2) a = 1.f / (1.f + __expf(-a));   // sigmoid for mask group
        om[obase + (k << 14)] = a;
    }
}

// ---------------- K2: deformable conv, NHWC gathers + MFMA.
// block = quarter-row (32 px), 4 waves; grid 2048.
// Phase A: 16-lane group = one (px,k); lane loads 4 taps x float4 channels
// (dense 256B segments), FMA-combines with premasked weights, ds_write_b64.
// K = 288 pairs in 3 tap-thirds (kt {0-2},{3-5},{6-8}); sl[32][100].
// LDS: params 864 + sl 3200 = 16,256 B.
__global__ __launch_bounds__(256) void k2_deform(
    const float* __restrict__ f1t, const unsigned* __restrict__ wmf,
    const float* __restrict__ om, float* __restrict__ aligned)
{
    extern __shared__ unsigned lds[];
    unsigned* pl_a = lds;            // [9][32] addr|dx<<14|dy<<15
    unsigned* pl_w = lds + 288;      // [9][32] x uint2 {half2(w00,w01), half2(w10,w11)}
    unsigned* sl   = lds + 864;      // [32 px][100] half2 samples (one third)

    int blk = blockIdx.x;        // b(2) y(7) xq(2)
    int xq = blk & 3;
    int y  = (blk >> 2) & 127;
    int b  = blk >> 9;

    int tid  = threadIdx.x;
    int lane = tid & 63;
    int wv   = tid >> 6;         // wave id = out-tile index r
    int row  = lane & 15;
    int ksel = lane >> 4;
    int chg  = lane & 15;        // phase-A channel group (4 ch)
    int ig   = lane >> 4;        // phase-A item subgroup 0..3

    const float* omb = om + ((b*27) << 14) + (y << 7);
    const float* ftb = f1t + (((size_t)b) << 20);   // b*16384*64

    // ---- param pre-phase: 288 items (k, px)
    for (int i = tid; i < 288; i += 256) {
        int k = i >> 5, lpx = i & 31;
        int gxp = xq*32 + lpx;
        float off0 = omb[((2*k)   << 14) + gxp];
        float off1 = omb[((2*k+1) << 14) + gxp];
        float mk   = omb[((18+k)  << 14) + gxp];   // sigmoided in K1

        float pyf = (float)y   + (float)(k/3) - 1.f + off0;
        float pxg = (float)gxp + (float)(k%3) - 1.f + off1;
        float fy = floorf(pyf), fx = floorf(pxg);
        int y0 = (int)fy, x0 = (int)fx;
        float wy = pyf - fy, wx = pxg - fx;
        float oy = 1.f - wy, ox = 1.f - wx;
        bool yv0 = (unsigned)y0     < (unsigned)HH;
        bool yv1 = (unsigned)(y0+1) < (unsigned)HH;
        bool xv0 = (unsigned)x0     < (unsigned)WW;
        bool xv1 = (unsigned)(x0+1) < (unsigned)WW;
        int y0c = min(max(y0, 0), 127);
        int x0c = min(max(x0, 0), 127);
        int dy = min(max(y0+1, 0), 127) - y0c;   // 0 or 1
        int dx = min(max(x0+1, 0), 127) - x0c;   // 0 or 1
        unsigned a = (unsigned)((y0c << 7) + x0c) | ((unsigned)dx << 14) | ((unsigned)dy << 15);
        float w00 = (yv0 && xv0) ? oy*ox*mk : 0.f;
        float w01 = (yv0 && xv1) ? oy*wx*mk : 0.f;
        float w10 = (yv1 && xv0) ? wy*ox*mk : 0.f;
        float w11 = (yv1 && xv1) ? wy*wx*mk : 0.f;
        pl_a[i] = a;
        pl_w[i*2]     = pk2u(w00, w01);
        pl_w[i*2 + 1] = pk2u(w10, w11);
    }
    __syncthreads();

    f32x4 acc0 = {0.f, 0.f, 0.f, 0.f};
    f32x4 acc1 = {0.f, 0.f, 0.f, 0.f};

    const unsigned* wbase = wmf + (wv*64 + lane)*72;

#pragma unroll 1
    for (int th = 0; th < 3; ++th) {
        // A-fragments for this third: 12 kb16 = 6 x dwordx4
        uint4 wq[6];
#pragma unroll
        for (int m = 0; m < 6; ++m)
            wq[m] = *(const uint4*)&wbase[th*24 + m*4];

        // phase A: 96 items (ktl,px); quad of items per wave-iteration
#pragma unroll 2
        for (int it = 0; it < 6; ++it) {
            int item = (it*4 + wv)*4 + ig;     // 0..95
            int ktl  = item >> 5;              // 0..2
            int px   = item & 31;
            int k    = th*3 + ktl;
            int pidx = k*32 + px;
            unsigned a = pl_a[pidx];
            uint2 wpk = *(const uint2*)&pl_w[pidx*2];
            int i00 = (int)(a & 0x3FFFu);
            int dx  = (int)((a >> 14) & 1u);
            int i10 = i00 + (((int)(a >> 15) & 1) << 7);
            h2 hw01 = u2h(wpk.x);
            h2 hw23 = u2h(wpk.y);
            float w00 = (float)hw01.x, w01 = (float)hw01.y;
            float w10 = (float)hw23.x, w11 = (float)hw23.y;

            f32x4 t00 = *(const f32x4*)&ftb[(size_t)(i00     )*64 + chg*4];
            f32x4 t01 = *(const f32x4*)&ftb[(size_t)(i00 + dx)*64 + chg*4];
            f32x4 t10 = *(const f32x4*)&ftb[(size_t)(i10     )*64 + chg*4];
            f32x4 t11 = *(const f32x4*)&ftb[(size_t)(i10 + dx)*64 + chg*4];

            f32x4 v = t00*w00;
            v += t01*w01;
            v += t10*w10;
            v += t11*w11;

            uint2 pkd;
            pkd.x = pk2u(v.x, v.y);            // channels 4chg, 4chg+1 -> cp 2chg
            pkd.y = pk2u(v.z, v.w);            // channels 4chg+2,+3   -> cp 2chg+1
            *(uint2*)&sl[px*100 + ktl*32 + 2*chg] = pkd;
        }
        __syncthreads();

        // phase B: 12 kb16 x 2 px-tiles MFMA
        const unsigned* b0p = &sl[(row     )*100 + ksel*2];
        const unsigned* b1p = &sl[(16+row  )*100 + ksel*2];
#pragma unroll
        for (int kbl = 0; kbl < 12; ++kbl) {
            U2H wa;
            uint4 q = wq[kbl >> 1];
            if (kbl & 1) { wa.u.x = q.z; wa.u.y = q.w; }
            else         { wa.u.x = q.x; wa.u.y = q.y; }
            U2H b0, b1;
            b0.u = *(const uint2*)&b0p[kbl*8];
            b1.u = *(const uint2*)&b1p[kbl*8];
            acc0 = __builtin_amdgcn_mfma_f32_16x16x16f16(wa.h, b0.h, acc0, 0, 0, 0);
            acc1 = __builtin_amdgcn_mfma_f32_16x16x16f16(wa.h, b1.h, acc1, 0, 0, 0);
        }
        __syncthreads();
    }

    // C/D: lane holds D[ksel*4 + rI][row] per px-tile
    int obase = ((b*CC) << 14) + (y << 7) + xq*32;
#pragma unroll
    for (int rI = 0; rI < 4; ++rI) {
        int och = wv*16 + ksel*4 + rI;
        aligned[obase + (och << 14) + row]      = acc0[rI];
        aligned[obase + (och << 14) + 16 + row] = acc1[rI];
    }
}

// ---------------- K3: per-channel partial sum / sumsq; grid 256 = (c, bimg)
__global__ __launch_bounds__(256) void k3_stats(
    const float* __restrict__ a, float* __restrict__ stats)
{
    int c = blockIdx.x & 63;
    int bimg = blockIdx.x >> 6;
    int tid = threadIdx.x;
    float s = 0.f, s2 = 0.f;
    const float* base = a + ((size_t)(bimg*CC + c) << 14);
    for (int i = tid*4; i < HWP; i += 256*4) {
        float4 v = *(const float4*)&base[i];
        s  += v.x + v.y + v.z + v.w;
        s2 += v.x*v.x + v.y*v.y + v.z*v.z + v.w*v.w;
    }
    for (int off = 32; off > 0; off >>= 1) {
        s  += __shfl_down(s,  off, 64);
        s2 += __shfl_down(s2, off, 64);
    }
    __shared__ float rs[4], rs2[4];
    int w = tid >> 6;
    if ((tid & 63) == 0) { rs[w] = s; rs2[w] = s2; }
    __syncthreads();
    if (tid == 0) {
        stats[bimg*128 + c]      = rs[0] + rs[1] + rs[2] + rs[3];
        stats[bimg*128 + 64 + c] = rs2[0] + rs2[1] + rs2[2] + rs2[3];
    }
}

// ---------------- K4: in-place normalize + affine (combines 4 partials)
__global__ __launch_bounds__(256) void k4_norm(
    float* __restrict__ a, const float* __restrict__ stats,
    const float* __restrict__ gamma, const float* __restrict__ beta)
{
    const float invN = 1.f / 65536.f;
    int n4 = (BB*CC*HWP) / 4;
    for (int i4 = blockIdx.x*256 + threadIdx.x; i4 < n4; i4 += gridDim.x*256) {
        int c = (i4 >> 12) & 63;
        float sm  = stats[c] + stats[128+c] + stats[256+c] + stats[384+c];
        float sq  = stats[64+c] + stats[192+c] + stats[320+c] + stats[448+c];
        float mean = sm * invN;
        float var  = sq * invN - mean*mean;
        float sc = gamma[c] * rsqrtf(var + 1e-5f);
        float sh = beta[c] - mean*sc;
        float4 v = ((const float4*)a)[i4];
        v.x = v.x*sc + sh; v.y = v.y*sc + sh;
        v.z = v.z*sc + sh; v.w = v.w*sc + sh;
        ((float4*)a)[i4] = v;
    }
}

extern "C" void kernel_launch(void* const* d_in, const int* in_sizes, int n_in,
                              void* d_out, int out_size, void* d_ws, size_t ws_size,
                              hipStream_t stream)
{
    const float* f1    = (const float*)d_in[0];
    const float* f3    = (const float*)d_in[1];
    const float* ow    = (const float*)d_in[2];
    const float* ob    = (const float*)d_in[3];
    const float* mw    = (const float*)d_in[4];
    const float* gamma = (const float*)d_in[5];
    const float* beta  = (const float*)d_in[6];
    float* out = (float*)d_out;

    float* om    = (float*)d_ws;                  // [4][27][128][128] = 7,077,888 B
    float* stats = om + 4*27*HWP;                 // [512] floats
    unsigned* owt2 = (unsigned*)(stats + 512);    // [3][64][96] u32 = 73,728 B
    unsigned* wmf  = owt2 + 3*64*96;              // [256][36][2] u32 = 73,728 B
    float* f1t   = (float*)(wmf + 18432);         // [4][128][128][64] = 16,777,216 B

    const int lds2 = (864 + 32*100) * 4;          // 16,256 B
    (void)hipFuncSetAttribute((const void*)k2_deform,
        hipFuncAttributeMaxDynamicSharedMemorySize, lds2);

    hipLaunchKernelGGL(k0_wt, dim3(133), dim3(256), 0, stream, ow, mw, owt2, wmf);
    hipLaunchKernelGGL(kT, dim3(512), dim3(256), 0, stream, f1, f1t);
    hipLaunchKernelGGL(k1_offset_conv, dim3(256, 3), dim3(256), 0, stream,
                       f1, f3, owt2, ob, om);
    hipLaunchKernelGGL(k2_deform, dim3(2048), dim3(256), lds2, stream,
                       f1t, wmf, om, out);
    hipLaunchKernelGGL(k3_stats, dim3(256), dim3(256), 0, stream, out, stats);
    hipLaunchKernelGGL(k4_norm, dim3(2048), dim3(256), 0, stream,
                       out, stats, gamma, beta);
}

// Round 13
// 99.439 us; speedup vs baseline: 8.8579x; 1.3036x over previous
//
#include <hip/hip_runtime.h>
#include <math.h>

#define BB 4
#define CC 64
#define HH 128
#define WW 128
#define HWP 16384

typedef _Float16 h2 __attribute__((ext_vector_type(2)));
typedef _Float16 h4 __attribute__((ext_vector_type(4)));
typedef __fp16  p2 __attribute__((ext_vector_type(2)));   // cvt_pkrtz's return type
typedef float f32x4 __attribute__((ext_vector_type(4)));
union HU { unsigned u; h2 h; p2 p; };
union U2H { uint2 u; h4 h; };
static __device__ __forceinline__ h2 u2h(unsigned x){ HU v; v.u = x; return v.h; }
static __device__ __forceinline__ unsigned pk2u(float a, float b){
    HU v; v.p = __builtin_amdgcn_cvt_pkrtz(a, b); return v.u;
}

// ---------------- kT: build f13t[b][y][x][64 pairs u32] (f16 channel pairs).
// pairs 0..31 = f1 channels (2cp,2cp+1); pairs 32..63 = f3 channels.
__global__ __launch_bounds__(256) void kT(
    const float* __restrict__ f1, const float* __restrict__ f3,
    unsigned* __restrict__ f13t)
{
    __shared__ float lt[64*129];
    int b = blockIdx.x >> 7, y = blockIdx.x & 127;
    int t = threadIdx.x;
    unsigned* dst = f13t + ((size_t)((b << 14) + (y << 7)))*64;
    for (int half = 0; half < 2; ++half) {
        const float* src = (half == 0 ? f1 : f3) + (((size_t)b*64) << 14) + (y << 7);
#pragma unroll 4
        for (int i = 0; i < 32; ++i) {
            int idx = i*256 + t; int c = idx >> 7, x = idx & 127;
            lt[c*129 + x] = src[(c << 14) + x];
        }
        __syncthreads();
#pragma unroll 4
        for (int i = 0; i < 16; ++i) {
            int idx = i*256 + t; int x = idx >> 5, cp = idx & 31;
            dst[x*64 + half*32 + cp] = pk2u(lt[(2*cp)*129 + x], lt[(2*cp+1)*129 + x]);
        }
        __syncthreads();
    }
}

// ---------------- K0: pack weights into MFMA A-fragments.
// wmf (k2 deform): u32 idx ((r*64+l)*36+kb)*2+j; P = kb*8+(l>>4)*2+j,
//   kt = P>>5, cp = P&31 (f1 pairs); out-ch r*16+(l&15).
// wof (k1 offset conv): u32 idx ((mt*64+l)*72+kb)*2+j; P = kb*8+(l>>4)*2+j
//   in [0,576); kt = P>>6 (tap), cp = P&63 (concat pair); och = mt*16+(l&15),
//   zero when och >= 27.
__global__ __launch_bounds__(256) void k0_wt(
    const float* __restrict__ ow, const float* __restrict__ mw,
    unsigned* __restrict__ wmf, unsigned* __restrict__ wof)
{
    int i = blockIdx.x*256 + threadIdx.x;
    if (i < 18432) {                           // wmf: 4*64*36*2
        int j   = i & 1;
        int t2  = i >> 1;
        int kb  = t2 % 36;
        int rl  = t2 / 36;
        int l   = rl & 63;
        int r   = rl >> 6;
        int row = l & 15, ksel = l >> 4;
        int och = r*16 + row;
        int P   = kb*8 + ksel*2 + j;           // 0..287
        int kt  = P >> 5;
        int cp  = P & 31;
        float lo = mw[och*576 + (2*cp    )*9 + kt];
        float hi = mw[och*576 + (2*cp + 1)*9 + kt];
        wmf[i] = pk2u(lo, hi);
    } else if (i < 36864) {                    // wof: 2*64*72*2
        int idx = i - 18432;
        int j   = idx & 1;
        int t2  = idx >> 1;
        int kb  = t2 % 72;
        int rl  = t2 / 72;
        int l   = rl & 63;
        int mt  = rl >> 6;
        int row = l & 15, ksel = l >> 4;
        int och = mt*16 + row;
        int P   = kb*8 + ksel*2 + j;           // 0..575
        int kt  = P >> 6;                      // tap 0..8
        int cp  = P & 63;                      // concat pair
        unsigned v = 0;
        if (och < 27) {
            float lo = ow[(och*128 + 2*cp    )*9 + kt];
            float hi = ow[(och*128 + 2*cp + 1)*9 + kt];
            v = pk2u(lo, hi);
        }
        wof[idx] = v;
    }
}

// ---------------- K1: offset conv via MFMA. block = quarter-row (32 px),
// 4 waves = 2 M-tiles x 2 px-tiles; K = 576 pairs in 3 tap-row chunks.
// tile[34][68] u32 = one input row slab (halo + zero-pad), dense uint4 loads.
__global__ __launch_bounds__(256) void k1_offset_conv(
    const unsigned* __restrict__ f13t, const unsigned* __restrict__ wof,
    const float* __restrict__ ob, float* __restrict__ om)
{
    __shared__ unsigned tile[34*68];

    int blk = blockIdx.x;        // b(2) y(7) xq(2)
    int xq = blk & 3;
    int y  = (blk >> 2) & 127;
    int b  = blk >> 9;

    int tid  = threadIdx.x;
    int lane = tid & 63;
    int wv   = tid >> 6;
    int mt   = wv >> 1;          // M-tile (out-ch 16*mt..)
    int pxt  = wv & 1;           // px-tile
    int row  = lane & 15;
    int ksel = lane >> 4;

    f32x4 acc = {0.f, 0.f, 0.f, 0.f};
    const unsigned* wbase = wof + (size_t)(mt*64 + lane)*144;

#pragma unroll 1
    for (int dy = 0; dy < 3; ++dy) {
        int yy = y + dy - 1;
        bool yok = (unsigned)yy < (unsigned)HH;
        // stage tile: 34 px slots x 16 uint4 (64 pairs)
        __syncthreads();
        for (int i = tid; i < 544; i += 256) {
            int px34 = i >> 4, q = i & 15;
            int gxp = xq*32 - 1 + px34;
            uint4 v = make_uint4(0u, 0u, 0u, 0u);
            if (yok && (unsigned)gxp < (unsigned)WW)
                v = *(const uint4*)&f13t[(((size_t)(b*128 + yy))*128 + gxp)*64 + q*4];
            *(uint4*)&tile[px34*68 + q*4] = v;
        }
        __syncthreads();

        // 24 K-blocks in 2 halves of 12 (A-frags 6 uint4 at a time)
#pragma unroll
        for (int hf = 0; hf < 2; ++hf) {
            uint4 wq[6];
#pragma unroll
            for (int m = 0; m < 6; ++m)
                wq[m] = *(const uint4*)&wbase[dy*48 + hf*24 + m*4];
#pragma unroll
            for (int kl = 0; kl < 12; ++kl) {
                int Pl  = (hf*12 + kl)*8 + ksel*2;   // pair in chunk [0,192)
                int ktl = Pl >> 6;                   // dx 0..2
                int cp  = Pl & 63;
                U2H wa;
                uint4 q = wq[kl >> 1];
                if (kl & 1) { wa.u.x = q.z; wa.u.y = q.w; }
                else        { wa.u.x = q.x; wa.u.y = q.y; }
                U2H bfr;
                bfr.u = *(const uint2*)&tile[(pxt*16 + row + ktl)*68 + cp];
                acc = __builtin_amdgcn_mfma_f32_16x16x16f16(wa.h, bfr.h, acc, 0, 0, 0);
            }
        }
    }

    // epilogue: och = mt*16 + ksel*4 + rI, px = pxt*16 + row
    int gx = xq*32 + pxt*16 + row;
#pragma unroll
    for (int rI = 0; rI < 4; ++rI) {
        int och = mt*16 + ksel*4 + rI;
        if (och < 27) {
            float v = acc[rI] + ob[och];
            if (och >= 18) v = 1.f / (1.f + __expf(-v));   // mask sigmoid
            om[((b*27 + och) << 14) + (y << 7) + gx] = v;
        }
    }
}

// ---------------- K2: deformable conv, NHWC f16-pair gathers + MFMA.
// block = quarter-row (32 px), 4 waves; grid 2048.
// LDS: params 864 + sl[32][100] = 16,256 B.
__global__ __launch_bounds__(256) void k2_deform(
    const unsigned* __restrict__ f13t, const unsigned* __restrict__ wmf,
    const float* __restrict__ om, float* __restrict__ aligned)
{
    extern __shared__ unsigned lds[];
    unsigned* pl_a = lds;            // [9][32] addr|dx<<14|dy<<15
    unsigned* pl_w = lds + 288;      // [9][32] x uint2 {half2(w00,w01), half2(w10,w11)}
    unsigned* sl   = lds + 864;      // [32 px][100] half2 samples (one third)

    int blk = blockIdx.x;        // b(2) y(7) xq(2)
    int xq = blk & 3;
    int y  = (blk >> 2) & 127;
    int b  = blk >> 9;

    int tid  = threadIdx.x;
    int lane = tid & 63;
    int wv   = tid >> 6;
    int row  = lane & 15;
    int ksel = lane >> 4;
    int chg  = lane & 15;        // phase-A channel group (4 ch = 2 pairs)
    int ig   = lane >> 4;        // phase-A item subgroup 0..3

    const float* omb = om + ((b*27) << 14) + (y << 7);
    const unsigned* ftb = f13t + (((size_t)b) << 20);

    // ---- param pre-phase: 288 items (k, px)
    for (int i = tid; i < 288; i += 256) {
        int k = i >> 5, lpx = i & 31;
        int gxp = xq*32 + lpx;
        float off0 = omb[((2*k)   << 14) + gxp];
        float off1 = omb[((2*k+1) << 14) + gxp];
        float mk   = omb[((18+k)  << 14) + gxp];   // sigmoided in K1

        float pyf = (float)y   + (float)(k/3) - 1.f + off0;
        float pxg = (float)gxp + (float)(k%3) - 1.f + off1;
        float fy = floorf(pyf), fx = floorf(pxg);
        int y0 = (int)fy, x0 = (int)fx;
        float wy = pyf - fy, wx = pxg - fx;
        float oy = 1.f - wy, ox = 1.f - wx;
        bool yv0 = (unsigned)y0     < (unsigned)HH;
        bool yv1 = (unsigned)(y0+1) < (unsigned)HH;
        bool xv0 = (unsigned)x0     < (unsigned)WW;
        bool xv1 = (unsigned)(x0+1) < (unsigned)WW;
        int y0c = min(max(y0, 0), 127);
        int x0c = min(max(x0, 0), 127);
        int dy = min(max(y0+1, 0), 127) - y0c;   // 0 or 1
        int dx = min(max(x0+1, 0), 127) - x0c;   // 0 or 1
        unsigned a = (unsigned)((y0c << 7) + x0c) | ((unsigned)dx << 14) | ((unsigned)dy << 15);
        float w00 = (yv0 && xv0) ? oy*ox*mk : 0.f;
        float w01 = (yv0 && xv1) ? oy*wx*mk : 0.f;
        float w10 = (yv1 && xv0) ? wy*ox*mk : 0.f;
        float w11 = (yv1 && xv1) ? wy*wx*mk : 0.f;
        pl_a[i] = a;
        pl_w[i*2]     = pk2u(w00, w01);
        pl_w[i*2 + 1] = pk2u(w10, w11);
    }
    __syncthreads();

    f32x4 acc0 = {0.f, 0.f, 0.f, 0.f};
    f32x4 acc1 = {0.f, 0.f, 0.f, 0.f};

    const unsigned* wbase = wmf + (wv*64 + lane)*72;

#pragma unroll 1
    for (int th = 0; th < 3; ++th) {
        uint4 wq[6];
#pragma unroll
        for (int m = 0; m < 6; ++m)
            wq[m] = *(const uint4*)&wbase[th*24 + m*4];

        // phase A: 96 items (ktl,px); lane group of 16 = one item
#pragma unroll 2
        for (int it = 0; it < 6; ++it) {
            int item = (it*4 + wv)*4 + ig;     // 0..95
            int ktl  = item >> 5;              // 0..2
            int px   = item & 31;
            int k    = th*3 + ktl;
            int pidx = k*32 + px;
            unsigned a = pl_a[pidx];
            uint2 wpk = *(const uint2*)&pl_w[pidx*2];
            int i00 = (int)(a & 0x3FFFu);
            int dx  = (int)((a >> 14) & 1u);
            int i10 = i00 + (((int)(a >> 15) & 1) << 7);
            h2 hw01 = u2h(wpk.x);
            h2 hw23 = u2h(wpk.y);
            float w00 = (float)hw01.x, w01 = (float)hw01.y;
            float w10 = (float)hw23.x, w11 = (float)hw23.y;

            uint2 r00 = *(const uint2*)&ftb[(size_t)(i00     )*64 + 2*chg];
            uint2 r01 = *(const uint2*)&ftb[(size_t)(i00 + dx)*64 + 2*chg];
            uint2 r10 = *(const uint2*)&ftb[(size_t)(i10     )*64 + 2*chg];
            uint2 r11 = *(const uint2*)&ftb[(size_t)(i10 + dx)*64 + 2*chg];

            h2 a00 = u2h(r00.x), b00 = u2h(r00.y);
            h2 a01 = u2h(r01.x), b01 = u2h(r01.y);
            h2 a10 = u2h(r10.x), b10 = u2h(r10.y);
            h2 a11 = u2h(r11.x), b11 = u2h(r11.y);

            float v0 = w00*(float)a00.x + w01*(float)a01.x + w10*(float)a10.x + w11*(float)a11.x;
            float v1 = w00*(float)a00.y + w01*(float)a01.y + w10*(float)a10.y + w11*(float)a11.y;
            float v2 = w00*(float)b00.x + w01*(float)b01.x + w10*(float)b10.x + w11*(float)b11.x;
            float v3 = w00*(float)b00.y + w01*(float)b01.y + w10*(float)b10.y + w11*(float)b11.y;

            uint2 pkd;
            pkd.x = pk2u(v0, v1);
            pkd.y = pk2u(v2, v3);
            *(uint2*)&sl[px*100 + ktl*32 + 2*chg] = pkd;
        }
        __syncthreads();

        // phase B: 12 kb16 x 2 px-tiles MFMA
        const unsigned* b0p = &sl[(row     )*100 + ksel*2];
        const unsigned* b1p = &sl[(16+row  )*100 + ksel*2];
#pragma unroll
        for (int kbl = 0; kbl < 12; ++kbl) {
            U2H wa;
            uint4 q = wq[kbl >> 1];
            if (kbl & 1) { wa.u.x = q.z; wa.u.y = q.w; }
            else         { wa.u.x = q.x; wa.u.y = q.y; }
            U2H b0, b1;
            b0.u = *(const uint2*)&b0p[kbl*8];
            b1.u = *(const uint2*)&b1p[kbl*8];
            acc0 = __builtin_amdgcn_mfma_f32_16x16x16f16(wa.h, b0.h, acc0, 0, 0, 0);
            acc1 = __builtin_amdgcn_mfma_f32_16x16x16f16(wa.h, b1.h, acc1, 0, 0, 0);
        }
        __syncthreads();
    }

    int obase = ((b*CC) << 14) + (y << 7) + xq*32;
#pragma unroll
    for (int rI = 0; rI < 4; ++rI) {
        int och = wv*16 + ksel*4 + rI;
        aligned[obase + (och << 14) + row]      = acc0[rI];
        aligned[obase + (och << 14) + 16 + row] = acc1[rI];
    }
}

// ---------------- K3: per-channel partial sum / sumsq; grid 256 = (c, bimg)
__global__ __launch_bounds__(256) void k3_stats(
    const float* __restrict__ a, float* __restrict__ stats)
{
    int c = blockIdx.x & 63;
    int bimg = blockIdx.x >> 6;
    int tid = threadIdx.x;
    float s = 0.f, s2 = 0.f;
    const float* base = a + ((size_t)(bimg*CC + c) << 14);
    for (int i = tid*4; i < HWP; i += 256*4) {
        float4 v = *(const float4*)&base[i];
        s  += v.x + v.y + v.z + v.w;
        s2 += v.x*v.x + v.y*v.y + v.z*v.z + v.w*v.w;
    }
    for (int off = 32; off > 0; off >>= 1) {
        s  += __shfl_down(s,  off, 64);
        s2 += __shfl_down(s2, off, 64);
    }
    __shared__ float rs[4], rs2[4];
    int w = tid >> 6;
    if ((tid & 63) == 0) { rs[w] = s; rs2[w] = s2; }
    __syncthreads();
    if (tid == 0) {
        stats[bimg*128 + c]      = rs[0] + rs[1] + rs[2] + rs[3];
        stats[bimg*128 + 64 + c] = rs2[0] + rs2[1] + rs2[2] + rs2[3];
    }
}

// ---------------- K4: in-place normalize + affine (combines 4 partials)
__global__ __launch_bounds__(256) void k4_norm(
    float* __restrict__ a, const float* __restrict__ stats,
    const float* __restrict__ gamma, const float* __restrict__ beta)
{
    const float invN = 1.f / 65536.f;
    int n4 = (BB*CC*HWP) / 4;
    for (int i4 = blockIdx.x*256 + threadIdx.x; i4 < n4; i4 += gridDim.x*256) {
        int c = (i4 >> 12) & 63;
        float sm  = stats[c] + stats[128+c] + stats[256+c] + stats[384+c];
        float sq  = stats[64+c] + stats[192+c] + stats[320+c] + stats[448+c];
        float mean = sm * invN;
        float var  = sq * invN - mean*mean;
        float sc = gamma[c] * rsqrtf(var + 1e-5f);
        float sh = beta[c] - mean*sc;
        float4 v = ((const float4*)a)[i4];
        v.x = v.x*sc + sh; v.y = v.y*sc + sh;
        v.z = v.z*sc + sh; v.w = v.w*sc + sh;
        ((float4*)a)[i4] = v;
    }
}

extern "C" void kernel_launch(void* const* d_in, const int* in_sizes, int n_in,
                              void* d_out, int out_size, void* d_ws, size_t ws_size,
                              hipStream_t stream)
{
    const float* f1    = (const float*)d_in[0];
    const float* f3    = (const float*)d_in[1];
    const float* ow    = (const float*)d_in[2];
    const float* ob    = (const float*)d_in[3];
    const float* mw    = (const float*)d_in[4];
    const float* gamma = (const float*)d_in[5];
    const float* beta  = (const float*)d_in[6];
    float* out = (float*)d_out;

    float* om     = (float*)d_ws;                 // [4][27][128][128] = 7,077,888 B
    float* stats  = om + 4*27*HWP;                // [512] floats
    unsigned* wmf = (unsigned*)(stats + 512);     // 18432 u32 = 73,728 B
    unsigned* wof = wmf + 18432;                  // 18432 u32 = 73,728 B
    unsigned* f13t = wof + 18432;                 // [4][128][128][64] u32 = 16,777,216 B

    const int lds2 = (864 + 32*100) * 4;          // 16,256 B
    (void)hipFuncSetAttribute((const void*)k2_deform,
        hipFuncAttributeMaxDynamicSharedMemorySize, lds2);

    hipLaunchKernelGGL(k0_wt, dim3(144), dim3(256), 0, stream, ow, mw, wmf, wof);
    hipLaunchKernelGGL(kT, dim3(512), dim3(256), 0, stream, f1, f3, f13t);
    hipLaunchKernelGGL(k1_offset_conv, dim3(2048), dim3(256), 0, stream,
                       f13t, wof, ob, om);
    hipLaunchKernelGGL(k2_deform, dim3(2048), dim3(256), lds2, stream,
                       f13t, wmf, om, out);
    hipLaunchKernelGGL(k3_stats, dim3(256), dim3(256), 0, stream, out, stats);
    hipLaunchKernelGGL(k4_norm, dim3(2048), dim3(256), 0, stream,
                       out, stats, gamma, beta);
}